// Round 5
// baseline (10714.718 us; speedup 1.0000x reference)
//
#include <hip/hip_runtime.h>

#define TB  512
#define TT  2048
#define HID 32

// Recurrent core in fp64: fp32's per-step dot/update rounding bias accumulates
// coherently over T=2048 (integrator units), landing ~6e-4 at the output —
// same error class as the 5.2e-4 threshold. fp64 feedback path steps below it.
// Input-path dots (non-recurrent, random-sign per t) stay fp32.

// ---- fp64 recurrent h-dot: m-row (32) + n-half (16) per lane ----
#define GRU_HDOT_D()                                                         \
    double a0=0.,a1=0.,a2=0.,a3=0.;                                          \
    _Pragma("unroll")                                                        \
    for (int k=0;k<8;k++){                                                   \
      a0 = fma(wh_m[4*k+0], hreg[4*k+0], a0);                                \
      a1 = fma(wh_m[4*k+1], hreg[4*k+1], a1);                                \
      a2 = fma(wh_m[4*k+2], hreg[4*k+2], a2);                                \
      a3 = fma(wh_m[4*k+3], hreg[4*k+3], a3);                                \
    }                                                                        \
    double hm = (a0+a1)+(a2+a3);                                             \
    double c0=0.,c1=0.;                                                      \
    _Pragma("unroll")                                                        \
    for (int k=0;k<8;k++){                                                   \
      c0 = fma(wh_n[2*k+0], hnd[2*k+0], c0);                                 \
      c1 = fma(wh_n[2*k+1], hnd[2*k+1], c1);                                 \
    }                                                                        \
    double sn_h = c0+c1;

// half0 lane: r = sigma(v_r); half1 lane: w = 1-z = sigma(-v_z). All fp64.
// h' = h + w*(n-h).
#define GRU_GATES_D()                                                        \
    double vm   = hm + (double)sx + b_m;                                     \
    double varg = half ? -vm : vm;                                           \
    double gm   = 1.0/(1.0 + exp(-varg));                                    \
    double wf   = __shfl_xor(gm,   32, 64);                                  \
    float  xn_o = __shfl_xor(sn_x, 32, 64);                                  \
    double hn_o = __shfl_xor(sn_h, 32, 64);                                  \
    double xn = (double)sn_x + (double)xn_o + b_ihn;                         \
    double hn = sn_h + hn_o + b_hhn;                                         \
    double nn = tanh(fma(gm, hn, xn));                                       \
    double hnew = fma(wf, nn - hj, hj);                                      \
    hj = hnew;

#define GRU_READBACK_D()                                                     \
    {                                                                        \
      const double2* h2 = (const double2*)hlds;                              \
      _Pragma("unroll")                                                      \
      for (int q=0;q<16;q++){ double2 v=h2[q];                               \
        hreg[2*q]=v.x; hreg[2*q+1]=v.y; }                                    \
      const double2* hx2 = (const double2*)(hlds + half*16);                 \
      _Pragma("unroll")                                                      \
      for (int q=0;q<8;q++){ double2 v=hx2[q];                               \
        hnd[2*q]=v.x; hnd[2*q+1]=v.y; }                                      \
    }

// ---------------- Layer 0: fused input-GEMM (K=6, fp32) + fp64 GRU scan ----------------
#define L0_STEP(XV)                                                          \
  {                                                                          \
    float sx = 0.f;                                                          \
    sx = fmaf(wi_m[0], XV[0], sx); sx = fmaf(wi_m[1], XV[1], sx);            \
    sx = fmaf(wi_m[2], XV[2], sx); sx = fmaf(wi_m[3], XV[3], sx);            \
    sx = fmaf(wi_m[4], XV[4], sx); sx = fmaf(wi_m[5], XV[5], sx);            \
    float xn0 = half ? XV[3] : XV[0];                                        \
    float xn1 = half ? XV[4] : XV[1];                                        \
    float xn2 = half ? XV[5] : XV[2];                                        \
    float sn_x = fmaf(wi_n[0], xn0, fmaf(wi_n[1], xn1, wi_n[2]*xn2));        \
    GRU_HDOT_D()                                                             \
    GRU_GATES_D()                                                            \
    if (lane < 32){ hlds[j] = hnew; hout[j] = (float)hnew; }                 \
    hout += hinc;                                                            \
    GRU_READBACK_D()                                                         \
  }

__global__ __launch_bounds__(64,1)
void gru_l0(const float* __restrict__ x,          // already offset to chunk base
            const float* __restrict__ Wih_f, const float* __restrict__ Whh_f,
            const float* __restrict__ bih_f, const float* __restrict__ bhh_f,
            const float* __restrict__ Wih_b, const float* __restrict__ Whh_b,
            const float* __restrict__ bih_b, const float* __restrict__ bhh_b,
            float* __restrict__ h0)               // chunk-local [bc][T][64]
{
  const int job  = blockIdx.x;
  const int b    = job >> 1;
  const int dir  = job & 1;
  const int lane = threadIdx.x;
  const int j    = lane & 31;
  const int half = lane >> 5;

  const float* Wih = dir ? Wih_b : Wih_f;
  const float* Whh = dir ? Whh_b : Whh_f;
  const float* bih = dir ? bih_b : bih_f;
  const float* bhh = dir ? bhh_b : bhh_f;

  const int mrow = half * 32 + j;   // r-row (half0) or z-row (half1)
  const int nrow = 64 + j;          // n-row

  double wh_m[32], wh_n[16];
  float  wi_m[6], wi_n[3];
  {
    const float4* wm4 = (const float4*)(Whh + mrow*32);
#pragma unroll
    for (int q=0;q<8;q++){ float4 v=wm4[q];
      wh_m[4*q]=(double)v.x; wh_m[4*q+1]=(double)v.y;
      wh_m[4*q+2]=(double)v.z; wh_m[4*q+3]=(double)v.w; }
    const float4* wn4 = (const float4*)(Whh + nrow*32 + half*16);
#pragma unroll
    for (int q=0;q<4;q++){ float4 v=wn4[q];
      wh_n[4*q]=(double)v.x; wh_n[4*q+1]=(double)v.y;
      wh_n[4*q+2]=(double)v.z; wh_n[4*q+3]=(double)v.w; }
#pragma unroll
    for (int i=0;i<6;i++) wi_m[i] = Wih[mrow*6+i];
#pragma unroll
    for (int i=0;i<3;i++) wi_n[i] = Wih[nrow*6 + half*3 + i];
  }
  const double b_m   = (double)bih[mrow] + (double)bhh[mrow];
  const double b_ihn = (double)bih[nrow];
  const double b_hhn = (double)bhh[nrow];

  __shared__ __align__(16) double hlds[32];

  double hreg[32], hnd[16];
#pragma unroll
  for (int k=0;k<32;k++) hreg[k]=0.;
#pragma unroll
  for (int k=0;k<16;k++) hnd[k]=0.;
  double hj = 0.;

  const long t0    = dir ? (TT-1) : 0;
  const long tstep = dir ? -1 : 1;
  const float* xrow = x + ((size_t)b*TT + t0)*6;
  const long  xinc = tstep*6;
  float* hout = h0 + ((size_t)b*TT + t0)*64 + dir*32;
  const long hinc = tstep*64;

  float xa[6], xb[6];
  {
    const float2* p=(const float2*)xrow;
    xa[0]=p[0].x; xa[1]=p[0].y; xa[2]=p[1].x; xa[3]=p[1].y; xa[4]=p[2].x; xa[5]=p[2].y;
    const float2* q=(const float2*)(xrow + xinc);
    xb[0]=q[0].x; xb[1]=q[0].y; xb[2]=q[1].x; xb[3]=q[1].y; xb[4]=q[2].x; xb[5]=q[2].y;
  }
  const float* xld = xrow + 2*xinc;

#pragma unroll 1
  for (int it=0; it<TT; it+=2){
    L0_STEP(xa)
    if (it+2 < TT){
      const float2* p=(const float2*)xld;
      xa[0]=p[0].x; xa[1]=p[0].y; xa[2]=p[1].x; xa[3]=p[1].y; xa[4]=p[2].x; xa[5]=p[2].y;
      xld += xinc;
    }
    L0_STEP(xb)
    if (it+3 < TT){
      const float2* p=(const float2*)xld;
      xb[0]=p[0].x; xb[1]=p[0].y; xb[2]=p[1].x; xb[3]=p[1].y; xb[4]=p[2].x; xb[5]=p[2].y;
      xld += xinc;
    }
  }
}

// ---------------- Layer 1: fused input-GEMM (K=64, fp32) + fp64 GRU scan + mean ----------------
#define L1_STEP(S)                                                           \
  {                                                                          \
    const float* sl = ring + (S)*64;                                         \
    float m0=0.f,m1=0.f,m2=0.f,m3=0.f;                                       \
    const float4* s4 = (const float4*)sl;                                    \
    _Pragma("unroll")                                                        \
    for (int q=0;q<16;q++){ float4 v=s4[q];                                  \
      m0=fmaf(wi_m[4*q+0],v.x,m0); m1=fmaf(wi_m[4*q+1],v.y,m1);              \
      m2=fmaf(wi_m[4*q+2],v.z,m2); m3=fmaf(wi_m[4*q+3],v.w,m3); }            \
    float sx = ((m0+m1)+(m2+m3));                                            \
    float n0=0.f,n1=0.f;                                                     \
    const float4* sn4 = (const float4*)(sl + half*32);                       \
    _Pragma("unroll")                                                        \
    for (int q=0;q<8;q++){ float4 v=sn4[q];                                  \
      n0=fmaf(wi_n[4*q+0],v.x,n0); n1=fmaf(wi_n[4*q+1],v.y,n1);              \
      n0=fmaf(wi_n[4*q+2],v.z,n0); n1=fmaf(wi_n[4*q+3],v.w,n1); }            \
    float sn_x = n0+n1;                                                      \
    GRU_HDOT_D()                                                             \
    GRU_GATES_D()                                                            \
    psum += hnew;                                                            \
    if (lane < 32) hlds[j] = hnew;                                           \
    GRU_READBACK_D()                                                         \
  }

__global__ __launch_bounds__(64,1)
void gru_l1(const float* __restrict__ h0,         // chunk-local [bc][T][64]
            const float* __restrict__ Wih_f, const float* __restrict__ Whh_f,
            const float* __restrict__ bih_f, const float* __restrict__ bhh_f,
            const float* __restrict__ Wih_b, const float* __restrict__ Whh_b,
            const float* __restrict__ bih_b, const float* __restrict__ bhh_b,
            float* __restrict__ pooled)           // already offset to chunk base
{
  const int job  = blockIdx.x;
  const int b    = job >> 1;
  const int dir  = job & 1;
  const int lane = threadIdx.x;
  const int j    = lane & 31;
  const int half = lane >> 5;

  const float* Wih = dir ? Wih_b : Wih_f;
  const float* Whh = dir ? Whh_b : Whh_f;
  const float* bih = dir ? bih_b : bih_f;
  const float* bhh = dir ? bhh_b : bhh_f;

  const int mrow = half * 32 + j;
  const int nrow = 64 + j;

  float  wi_m[64], wi_n[32];
  double wh_m[32], wh_n[16];
  {
    const float4* wm4 = (const float4*)(Wih + mrow*64);
#pragma unroll
    for (int q=0;q<16;q++){ float4 v=wm4[q];
      wi_m[4*q]=v.x; wi_m[4*q+1]=v.y; wi_m[4*q+2]=v.z; wi_m[4*q+3]=v.w; }
    const float4* wn4 = (const float4*)(Wih + nrow*64 + half*32);
#pragma unroll
    for (int q=0;q<8;q++){ float4 v=wn4[q];
      wi_n[4*q]=v.x; wi_n[4*q+1]=v.y; wi_n[4*q+2]=v.z; wi_n[4*q+3]=v.w; }
    const float4* hm4 = (const float4*)(Whh + mrow*32);
#pragma unroll
    for (int q=0;q<8;q++){ float4 v=hm4[q];
      wh_m[4*q]=(double)v.x; wh_m[4*q+1]=(double)v.y;
      wh_m[4*q+2]=(double)v.z; wh_m[4*q+3]=(double)v.w; }
    const float4* hn4 = (const float4*)(Whh + nrow*32 + half*16);
#pragma unroll
    for (int q=0;q<4;q++){ float4 v=hn4[q];
      wh_n[4*q]=(double)v.x; wh_n[4*q+1]=(double)v.y;
      wh_n[4*q+2]=(double)v.z; wh_n[4*q+3]=(double)v.w; }
  }
  const double b_m   = (double)bih[mrow] + (double)bhh[mrow];
  const double b_ihn = (double)bih[nrow];
  const double b_hhn = (double)bhh[nrow];

  __shared__ __align__(16) double hlds[32];
  __shared__ __align__(16) float  ring[4*64];

  double hreg[32], hnd[16];
#pragma unroll
  for (int k=0;k<32;k++) hreg[k]=0.;
#pragma unroll
  for (int k=0;k<16;k++) hnd[k]=0.;
  double hj = 0.;
  double psum = 0.;

  const float* h0b = h0 + (size_t)b*TT*64;

  // prologue: stage rows 0..2 into slots 0..2; rows 3,4 in flight in sA,sB
  {
    const float* p0 = h0b + (size_t)(dir ? (TT-1-0) : 0)*64;
    const float* p1 = h0b + (size_t)(dir ? (TT-1-1) : 1)*64;
    const float* p2 = h0b + (size_t)(dir ? (TT-1-2) : 2)*64;
    float r0 = p0[lane], r1 = p1[lane], r2 = p2[lane];
    ring[0*64+lane]=r0; ring[1*64+lane]=r1; ring[2*64+lane]=r2;
  }
  float sA, sB;
  { const float* p = h0b + (size_t)(dir ? (TT-1-3) : 3)*64; sA = p[lane]; }
  { const float* p = h0b + (size_t)(dir ? (TT-1-4) : 4)*64; sB = p[lane]; }

#pragma unroll 1
  for (int it=0; it<TT; it+=2){
    L1_STEP(it & 3)
    ring[((it+3)&3)*64 + lane] = sA;                 // row it+3 becomes visible
    { int lt = it+5; if (lt > TT-1) lt = TT-1;
      const float* p = h0b + (size_t)(dir ? (TT-1-lt) : lt)*64; sA = p[lane]; }
    L1_STEP((it+1) & 3)
    ring[((it+4)&3)*64 + lane] = sB;                 // row it+4
    { int lt = it+6; if (lt > TT-1) lt = TT-1;
      const float* p = h0b + (size_t)(dir ? (TT-1-lt) : lt)*64; sB = p[lane]; }
  }

  if (lane < 32) pooled[(size_t)b*64 + dir*32 + j] = (float)psum;
}

// ---------------- FC head: mean -> fc1(relu) -> fc2 ----------------
__global__ void fc_ep(const float* __restrict__ pooled,
                      const float* __restrict__ fc1w, const float* __restrict__ fc1b,
                      const float* __restrict__ fc2w, const float* __restrict__ fc2b,
                      float* __restrict__ out)
{
  int b = blockIdx.x*blockDim.x + threadIdx.x;
  if (b >= TB) return;
  float v[64];
  const float4* p4 = (const float4*)(pooled + (size_t)b*64);
#pragma unroll
  for (int q=0;q<16;q++){ float4 t=p4[q];
    v[4*q]  =t.x*(1.f/TT); v[4*q+1]=t.y*(1.f/TT);
    v[4*q+2]=t.z*(1.f/TT); v[4*q+3]=t.w*(1.f/TT); }
  float acc = fc2b[0];
#pragma unroll
  for (int g=0; g<16; g++){
    float s = fc1b[g];
    const float4* w4 = (const float4*)(fc1w + g*64);
#pragma unroll
    for (int q=0;q<16;q++){ float4 w=w4[q];
      s=fmaf(w.x,v[4*q],s);   s=fmaf(w.y,v[4*q+1],s);
      s=fmaf(w.z,v[4*q+2],s); s=fmaf(w.w,v[4*q+3],s); }
    s = fmaxf(s, 0.f);
    acc = fmaf(fc2w[g], s, acc);
  }
  out[b] = acc;
}

extern "C" void kernel_launch(void* const* d_in, const int* in_sizes, int n_in,
                              void* d_out, int out_size, void* d_ws, size_t ws_size,
                              hipStream_t stream)
{
  (void)in_sizes; (void)n_in; (void)out_size;

  const float* x     = (const float*)d_in[0];
  const float* Wih0f = (const float*)d_in[1];
  const float* Whh0f = (const float*)d_in[2];
  const float* bih0f = (const float*)d_in[3];
  const float* bhh0f = (const float*)d_in[4];
  const float* Wih0b = (const float*)d_in[5];
  const float* Whh0b = (const float*)d_in[6];
  const float* bih0b = (const float*)d_in[7];
  const float* bhh0b = (const float*)d_in[8];
  const float* Wih1f = (const float*)d_in[9];
  const float* Whh1f = (const float*)d_in[10];
  const float* bih1f = (const float*)d_in[11];
  const float* bhh1f = (const float*)d_in[12];
  const float* Wih1b = (const float*)d_in[13];
  const float* Whh1b = (const float*)d_in[14];
  const float* bih1b = (const float*)d_in[15];
  const float* bhh1b = (const float*)d_in[16];
  const float* fc1w  = (const float*)d_in[17];
  const float* fc1b  = (const float*)d_in[18];
  const float* fc2w  = (const float*)d_in[19];
  const float* fc2b  = (const float*)d_in[20];

  // Workspace layout: pooled [TB][64] fp32 at front, then the h0 staging
  // region (fp32). If the full h0 [TB][TT][64] (256 MiB) does not fit in
  // ws_size, process the batch in evenly-sized chunks, reusing the h0
  // region (launch order on one stream serializes l0(c) -> l1(c)).
  const size_t POOLED_BYTES = (size_t)TB * 64 * sizeof(float);     // 128 KiB
  const size_t PER_B        = (size_t)TT * 64 * sizeof(float);     // 512 KiB
  float* pooled = (float*)d_ws;
  float* h0     = (float*)((char*)d_ws + POOLED_BYTES);

  size_t avail = (ws_size > POOLED_BYTES) ? (ws_size - POOLED_BYTES) : 0;
  int Bc = (int)(avail / PER_B);
  if (Bc < 1)  Bc = 1;          // last resort
  if (Bc > TB) Bc = TB;
  int nch = (TB + Bc - 1) / Bc;
  int Bce = (TB + nch - 1) / nch;   // evened chunk size

  for (int b0 = 0; b0 < TB; b0 += Bce) {
    int bc = (TB - b0 < Bce) ? (TB - b0) : Bce;
    hipLaunchKernelGGL(gru_l0, dim3(2*bc), dim3(64), 0, stream,
                       x + (size_t)b0*TT*6,
                       Wih0f,Whh0f,bih0f,bhh0f, Wih0b,Whh0b,bih0b,bhh0b, h0);
    hipLaunchKernelGGL(gru_l1, dim3(2*bc), dim3(64), 0, stream,
                       h0,
                       Wih1f,Whh1f,bih1f,bhh1f, Wih1b,Whh1b,bih1b,bhh1b,
                       pooled + (size_t)b0*64);
  }
  hipLaunchKernelGGL(fc_ep, dim3(2), dim3(256), 0, stream,
                     pooled, fc1w, fc1b, fc2w, fc2b, (float*)d_out);
}

// Round 6
// 6026.968 us; speedup vs baseline: 1.7778x; 1.7778x over previous
//
#include <hip/hip_runtime.h>

#define TB  512
#define TT  2048
#define HID 32

// Core recurrence in fp64 (state, broadcast, h-dots, update) — proven absmax 0.
// Nonlinearities in fp32 hardware exp2/rcp: their ~1e-6 errors enter h damped
// (by w for integrator units, by contraction for fast units) -> <=2e-5 at the
// output vs 5.2e-4 threshold. Removes the fp64 software exp/tanh latency chain.

// ---- fp64 recurrent h-dot: m-row (32) + n-half (16) per lane ----
#define GRU_HDOT_D()                                                         \
    double a0=0.,a1=0.,a2=0.,a3=0.;                                          \
    _Pragma("unroll")                                                        \
    for (int k=0;k<8;k++){                                                   \
      a0 = fma(wh_m[4*k+0], hreg[4*k+0], a0);                                \
      a1 = fma(wh_m[4*k+1], hreg[4*k+1], a1);                                \
      a2 = fma(wh_m[4*k+2], hreg[4*k+2], a2);                                \
      a3 = fma(wh_m[4*k+3], hreg[4*k+3], a3);                                \
    }                                                                        \
    double hm = (a0+a1)+(a2+a3);                                             \
    double c0=0.,c1=0.;                                                      \
    _Pragma("unroll")                                                        \
    for (int k=0;k<8;k++){                                                   \
      c0 = fma(wh_n[2*k+0], hnd[2*k+0], c0);                                 \
      c1 = fma(wh_n[2*k+1], hnd[2*k+1], c1);                                 \
    }                                                                        \
    double sn_h = c0+c1;

// half0 lane: r = sigma(v_r); half1 lane: w = 1-z = sigma(-v_z) (stable form).
// fp32 hw transcendentals; h' = h + w*(n-h) in fp64.
#define GRU_GATES_MIX()                                                      \
    double vm   = hm + (double)sx + b_m;                                     \
    float  vf   = (float)vm;                                                 \
    float  varg = half ? -vf : vf;                                           \
    float  ef   = __builtin_amdgcn_exp2f(varg * -1.44269504088896341f);      \
    float  gmf  = __builtin_amdgcn_rcpf(1.f + ef);                           \
    float  wf   = __shfl_xor(gmf,  32, 64);                                  \
    float  xn_o = __shfl_xor(sn_x, 32, 64);                                  \
    float  snhf = (float)sn_h;                                               \
    float  hn_o = __shfl_xor(snhf, 32, 64);                                  \
    double xn = (double)sn_x + (double)xn_o + b_ihn;                         \
    double hn = sn_h + (double)hn_o + b_hhn;                                 \
    float  af = (float)fma((double)gmf, hn, xn);                             \
    float  e2 = __builtin_amdgcn_exp2f(af * 2.88539008177792682f);           \
    float  nnf= 1.f - 2.f*__builtin_amdgcn_rcpf(1.f + e2);                   \
    double hnew = fma((double)wf, (double)nnf - hj, hj);                     \
    hj = hnew;

#define GRU_READBACK_D()                                                     \
    {                                                                        \
      const double2* h2 = (const double2*)hlds;                              \
      _Pragma("unroll")                                                      \
      for (int q=0;q<16;q++){ double2 v=h2[q];                               \
        hreg[2*q]=v.x; hreg[2*q+1]=v.y; }                                    \
      const double2* hx2 = (const double2*)(hlds + half*16);                 \
      _Pragma("unroll")                                                      \
      for (int q=0;q<8;q++){ double2 v=hx2[q];                               \
        hnd[2*q]=v.x; hnd[2*q+1]=v.y; }                                      \
    }

// ---------------- Layer 0: fused input-GEMM (K=6, fp32) + GRU scan ----------------
#define L0_STEP(XV)                                                          \
  {                                                                          \
    float sx = 0.f;                                                          \
    sx = fmaf(wi_m[0], XV[0], sx); sx = fmaf(wi_m[1], XV[1], sx);            \
    sx = fmaf(wi_m[2], XV[2], sx); sx = fmaf(wi_m[3], XV[3], sx);            \
    sx = fmaf(wi_m[4], XV[4], sx); sx = fmaf(wi_m[5], XV[5], sx);            \
    float xn0 = half ? XV[3] : XV[0];                                        \
    float xn1 = half ? XV[4] : XV[1];                                        \
    float xn2 = half ? XV[5] : XV[2];                                        \
    float sn_x = fmaf(wi_n[0], xn0, fmaf(wi_n[1], xn1, wi_n[2]*xn2));        \
    GRU_HDOT_D()                                                             \
    GRU_GATES_MIX()                                                          \
    if (lane < 32){ hlds[j] = hnew; hout[j] = (float)hnew; }                 \
    hout += hinc;                                                            \
    GRU_READBACK_D()                                                         \
  }

__global__ __launch_bounds__(64,1)
void gru_l0(const float* __restrict__ x,          // already offset to chunk base
            const float* __restrict__ Wih_f, const float* __restrict__ Whh_f,
            const float* __restrict__ bih_f, const float* __restrict__ bhh_f,
            const float* __restrict__ Wih_b, const float* __restrict__ Whh_b,
            const float* __restrict__ bih_b, const float* __restrict__ bhh_b,
            float* __restrict__ h0)               // chunk-local [bc][T][64]
{
  const int job  = blockIdx.x;
  const int b    = job >> 1;
  const int dir  = job & 1;
  const int lane = threadIdx.x;
  const int j    = lane & 31;
  const int half = lane >> 5;

  const float* Wih = dir ? Wih_b : Wih_f;
  const float* Whh = dir ? Whh_b : Whh_f;
  const float* bih = dir ? bih_b : bih_f;
  const float* bhh = dir ? bhh_b : bhh_f;

  const int mrow = half * 32 + j;   // r-row (half0) or z-row (half1)
  const int nrow = 64 + j;          // n-row

  double wh_m[32], wh_n[16];
  float  wi_m[6], wi_n[3];
  {
    const float4* wm4 = (const float4*)(Whh + mrow*32);
#pragma unroll
    for (int q=0;q<8;q++){ float4 v=wm4[q];
      wh_m[4*q]=(double)v.x; wh_m[4*q+1]=(double)v.y;
      wh_m[4*q+2]=(double)v.z; wh_m[4*q+3]=(double)v.w; }
    const float4* wn4 = (const float4*)(Whh + nrow*32 + half*16);
#pragma unroll
    for (int q=0;q<4;q++){ float4 v=wn4[q];
      wh_n[4*q]=(double)v.x; wh_n[4*q+1]=(double)v.y;
      wh_n[4*q+2]=(double)v.z; wh_n[4*q+3]=(double)v.w; }
#pragma unroll
    for (int i=0;i<6;i++) wi_m[i] = Wih[mrow*6+i];
#pragma unroll
    for (int i=0;i<3;i++) wi_n[i] = Wih[nrow*6 + half*3 + i];
  }
  const double b_m   = (double)bih[mrow] + (double)bhh[mrow];
  const double b_ihn = (double)bih[nrow];
  const double b_hhn = (double)bhh[nrow];

  __shared__ __align__(16) double hlds[32];

  double hreg[32], hnd[16];
#pragma unroll
  for (int k=0;k<32;k++) hreg[k]=0.;
#pragma unroll
  for (int k=0;k<16;k++) hnd[k]=0.;
  double hj = 0.;

  const long t0    = dir ? (TT-1) : 0;
  const long tstep = dir ? -1 : 1;
  const float* xrow = x + ((size_t)b*TT + t0)*6;
  const long  xinc = tstep*6;
  float* hout = h0 + ((size_t)b*TT + t0)*64 + dir*32;
  const long hinc = tstep*64;

  float xa[6], xb[6];
  {
    const float2* p=(const float2*)xrow;
    xa[0]=p[0].x; xa[1]=p[0].y; xa[2]=p[1].x; xa[3]=p[1].y; xa[4]=p[2].x; xa[5]=p[2].y;
    const float2* q=(const float2*)(xrow + xinc);
    xb[0]=q[0].x; xb[1]=q[0].y; xb[2]=q[1].x; xb[3]=q[1].y; xb[4]=q[2].x; xb[5]=q[2].y;
  }
  const float* xld = xrow + 2*xinc;

#pragma unroll 1
  for (int it=0; it<TT; it+=2){
    L0_STEP(xa)
    if (it+2 < TT){
      const float2* p=(const float2*)xld;
      xa[0]=p[0].x; xa[1]=p[0].y; xa[2]=p[1].x; xa[3]=p[1].y; xa[4]=p[2].x; xa[5]=p[2].y;
      xld += xinc;
    }
    L0_STEP(xb)
    if (it+3 < TT){
      const float2* p=(const float2*)xld;
      xb[0]=p[0].x; xb[1]=p[0].y; xb[2]=p[1].x; xb[3]=p[1].y; xb[4]=p[2].x; xb[5]=p[2].y;
      xld += xinc;
    }
  }
}

// ---------------- Layer 1: fused input-GEMM (K=64) + GRU scan + time-mean ----------------
// Input weights Wih1 (96x64) live in LDS (padded stride 68 floats -> start bank
// 17*row mod 32, bijective, conflict-light b128 reads) to kill the VGPR spill.
// Input-dot reads depend only on the prefetched ring -> off the h critical path.

#define L1_STEP(S)                                                           \
  {                                                                          \
    const float* sl = ring + (S)*64;                                         \
    const float4* s4 = (const float4*)sl;                                    \
    const float4* wm4 = (const float4*)(wlds + mrow*68);                     \
    float m0=0.f,m1=0.f,m2=0.f,m3=0.f;                                       \
    _Pragma("unroll")                                                        \
    for (int q=0;q<16;q++){ float4 v=s4[q]; float4 w=wm4[q];                 \
      m0=fmaf(w.x,v.x,m0); m1=fmaf(w.y,v.y,m1);                              \
      m2=fmaf(w.z,v.z,m2); m3=fmaf(w.w,v.w,m3); }                            \
    float sx = ((m0+m1)+(m2+m3));                                            \
    const float4* sn4 = (const float4*)(sl + half*32);                       \
    const float4* wn4 = (const float4*)(wlds + nrow*68 + half*32);           \
    float n0=0.f,n1=0.f;                                                     \
    _Pragma("unroll")                                                        \
    for (int q=0;q<8;q++){ float4 v=sn4[q]; float4 w=wn4[q];                 \
      n0=fmaf(w.x,v.x,n0); n1=fmaf(w.y,v.y,n1);                              \
      n0=fmaf(w.z,v.z,n0); n1=fmaf(w.w,v.w,n1); }                            \
    float sn_x = n0+n1;                                                      \
    GRU_HDOT_D()                                                             \
    GRU_GATES_MIX()                                                          \
    psum += hnew;                                                            \
    if (lane < 32) hlds[j] = hnew;                                           \
    GRU_READBACK_D()                                                         \
  }

__global__ __launch_bounds__(64,1)
void gru_l1(const float* __restrict__ h0,         // chunk-local [bc][T][64]
            const float* __restrict__ Wih_f, const float* __restrict__ Whh_f,
            const float* __restrict__ bih_f, const float* __restrict__ bhh_f,
            const float* __restrict__ Wih_b, const float* __restrict__ Whh_b,
            const float* __restrict__ bih_b, const float* __restrict__ bhh_b,
            float* __restrict__ pooled)           // already offset to chunk base
{
  const int job  = blockIdx.x;
  const int b    = job >> 1;
  const int dir  = job & 1;
  const int lane = threadIdx.x;
  const int j    = lane & 31;
  const int half = lane >> 5;

  const float* Wih = dir ? Wih_b : Wih_f;
  const float* Whh = dir ? Whh_b : Whh_f;
  const float* bih = dir ? bih_b : bih_f;
  const float* bhh = dir ? bhh_b : bhh_f;

  const int mrow = half * 32 + j;
  const int nrow = 64 + j;

  __shared__ __align__(16) float  wlds[96*68];
  __shared__ __align__(16) double hlds[32];
  __shared__ __align__(16) float  ring[4*64];

  // stage Wih (96x64) into padded LDS [96][68]
#pragma unroll 1
  for (int r=0; r<96; ++r) wlds[r*68 + lane] = Wih[r*64 + lane];

  double wh_m[32], wh_n[16];
  {
    const float4* hm4 = (const float4*)(Whh + mrow*32);
#pragma unroll
    for (int q=0;q<8;q++){ float4 v=hm4[q];
      wh_m[4*q]=(double)v.x; wh_m[4*q+1]=(double)v.y;
      wh_m[4*q+2]=(double)v.z; wh_m[4*q+3]=(double)v.w; }
    const float4* hn4 = (const float4*)(Whh + nrow*32 + half*16);
#pragma unroll
    for (int q=0;q<4;q++){ float4 v=hn4[q];
      wh_n[4*q]=(double)v.x; wh_n[4*q+1]=(double)v.y;
      wh_n[4*q+2]=(double)v.z; wh_n[4*q+3]=(double)v.w; }
  }
  const double b_m   = (double)bih[mrow] + (double)bhh[mrow];
  const double b_ihn = (double)bih[nrow];
  const double b_hhn = (double)bhh[nrow];

  double hreg[32], hnd[16];
#pragma unroll
  for (int k=0;k<32;k++) hreg[k]=0.;
#pragma unroll
  for (int k=0;k<16;k++) hnd[k]=0.;
  double hj = 0.;
  double psum = 0.;

  const float* h0b = h0 + (size_t)b*TT*64;

  // prologue: stage rows 0..2 into slots 0..2; rows 3,4 in flight in sA,sB
  {
    const float* p0 = h0b + (size_t)(dir ? (TT-1-0) : 0)*64;
    const float* p1 = h0b + (size_t)(dir ? (TT-1-1) : 1)*64;
    const float* p2 = h0b + (size_t)(dir ? (TT-1-2) : 2)*64;
    float r0 = p0[lane], r1 = p1[lane], r2 = p2[lane];
    ring[0*64+lane]=r0; ring[1*64+lane]=r1; ring[2*64+lane]=r2;
  }
  float sA, sB;
  { const float* p = h0b + (size_t)(dir ? (TT-1-3) : 3)*64; sA = p[lane]; }
  { const float* p = h0b + (size_t)(dir ? (TT-1-4) : 4)*64; sB = p[lane]; }

#pragma unroll 1
  for (int it=0; it<TT; it+=2){
    L1_STEP(it & 3)
    ring[((it+3)&3)*64 + lane] = sA;                 // row it+3 becomes visible
    { int lt = it+5; if (lt > TT-1) lt = TT-1;
      const float* p = h0b + (size_t)(dir ? (TT-1-lt) : lt)*64; sA = p[lane]; }
    L1_STEP((it+1) & 3)
    ring[((it+4)&3)*64 + lane] = sB;                 // row it+4
    { int lt = it+6; if (lt > TT-1) lt = TT-1;
      const float* p = h0b + (size_t)(dir ? (TT-1-lt) : lt)*64; sB = p[lane]; }
  }

  if (lane < 32) pooled[(size_t)b*64 + dir*32 + j] = (float)psum;
}

// ---------------- FC head: mean -> fc1(relu) -> fc2 ----------------
__global__ void fc_ep(const float* __restrict__ pooled,
                      const float* __restrict__ fc1w, const float* __restrict__ fc1b,
                      const float* __restrict__ fc2w, const float* __restrict__ fc2b,
                      float* __restrict__ out)
{
  int b = blockIdx.x*blockDim.x + threadIdx.x;
  if (b >= TB) return;
  float v[64];
  const float4* p4 = (const float4*)(pooled + (size_t)b*64);
#pragma unroll
  for (int q=0;q<16;q++){ float4 t=p4[q];
    v[4*q]  =t.x*(1.f/TT); v[4*q+1]=t.y*(1.f/TT);
    v[4*q+2]=t.z*(1.f/TT); v[4*q+3]=t.w*(1.f/TT); }
  float acc = fc2b[0];
#pragma unroll
  for (int g=0; g<16; g++){
    float s = fc1b[g];
    const float4* w4 = (const float4*)(fc1w + g*64);
#pragma unroll
    for (int q=0;q<16;q++){ float4 w=w4[q];
      s=fmaf(w.x,v[4*q],s);   s=fmaf(w.y,v[4*q+1],s);
      s=fmaf(w.z,v[4*q+2],s); s=fmaf(w.w,v[4*q+3],s); }
    s = fmaxf(s, 0.f);
    acc = fmaf(fc2w[g], s, acc);
  }
  out[b] = acc;
}

extern "C" void kernel_launch(void* const* d_in, const int* in_sizes, int n_in,
                              void* d_out, int out_size, void* d_ws, size_t ws_size,
                              hipStream_t stream)
{
  (void)in_sizes; (void)n_in; (void)out_size;

  const float* x     = (const float*)d_in[0];
  const float* Wih0f = (const float*)d_in[1];
  const float* Whh0f = (const float*)d_in[2];
  const float* bih0f = (const float*)d_in[3];
  const float* bhh0f = (const float*)d_in[4];
  const float* Wih0b = (const float*)d_in[5];
  const float* Whh0b = (const float*)d_in[6];
  const float* bih0b = (const float*)d_in[7];
  const float* bhh0b = (const float*)d_in[8];
  const float* Wih1f = (const float*)d_in[9];
  const float* Whh1f = (const float*)d_in[10];
  const float* bih1f = (const float*)d_in[11];
  const float* bhh1f = (const float*)d_in[12];
  const float* Wih1b = (const float*)d_in[13];
  const float* Whh1b = (const float*)d_in[14];
  const float* bih1b = (const float*)d_in[15];
  const float* bhh1b = (const float*)d_in[16];
  const float* fc1w  = (const float*)d_in[17];
  const float* fc1b  = (const float*)d_in[18];
  const float* fc2w  = (const float*)d_in[19];
  const float* fc2b  = (const float*)d_in[20];

  // Workspace: pooled [TB][64] fp32 at front, then the chunked h0 region.
  const size_t POOLED_BYTES = (size_t)TB * 64 * sizeof(float);     // 128 KiB
  const size_t PER_B        = (size_t)TT * 64 * sizeof(float);     // 512 KiB
  float* pooled = (float*)d_ws;
  float* h0     = (float*)((char*)d_ws + POOLED_BYTES);

  size_t avail = (ws_size > POOLED_BYTES) ? (ws_size - POOLED_BYTES) : 0;
  int Bc = (int)(avail / PER_B);
  if (Bc < 1)  Bc = 1;
  if (Bc > TB) Bc = TB;
  int nch = (TB + Bc - 1) / Bc;
  int Bce = (TB + nch - 1) / nch;

  for (int b0 = 0; b0 < TB; b0 += Bce) {
    int bc = (TB - b0 < Bce) ? (TB - b0) : Bce;
    hipLaunchKernelGGL(gru_l0, dim3(2*bc), dim3(64), 0, stream,
                       x + (size_t)b0*TT*6,
                       Wih0f,Whh0f,bih0f,bhh0f, Wih0b,Whh0b,bih0b,bhh0b, h0);
    hipLaunchKernelGGL(gru_l1, dim3(2*bc), dim3(64), 0, stream,
                       h0,
                       Wih1f,Whh1f,bih1f,bhh1f, Wih1b,Whh1b,bih1b,bhh1b,
                       pooled + (size_t)b0*64);
  }
  hipLaunchKernelGGL(fc_ep, dim3(2), dim3(256), 0, stream,
                     pooled, fc1w, fc1b, fc2w, fc2b, (float*)d_out);
}

// Round 7
// 4789.135 us; speedup vs baseline: 2.2373x; 1.2585x over previous
//
#include <hip/hip_runtime.h>

#define TB  512
#define TT  2048
#define HID 32

// Numeric scheme (proven, round 5/6: absmax 0.0): h-state, h-dots, update in
// fp64; gate transcendentals in fp32 hw exp2/rcp (errors enter damped);
// input-path dots fp32. w = 1-z = sigma(-v) stable form; h' = h + w*(n-h).

// ---------------- Layer 0: fused input-GEMM (K=6, fp32) + GRU scan ----------------
// One wave per (batch,dir). Lane pair (j, j+32): lane j computes r-gate row,
// lane j+32 computes z-gate row; BOTH halves compute the full n-row dot
// (full-row weights in regs) so no xn/hn cross-half shuffles -> only the
// gate-value shuffle (wf) remains, hidden under the tanh chain.

__global__ __launch_bounds__(64,1)
void gru_l0(const float* __restrict__ x,          // already offset to chunk base
            const float* __restrict__ Wih_f, const float* __restrict__ Whh_f,
            const float* __restrict__ bih_f, const float* __restrict__ bhh_f,
            const float* __restrict__ Wih_b, const float* __restrict__ Whh_b,
            const float* __restrict__ bih_b, const float* __restrict__ bhh_b,
            float* __restrict__ h0)               // chunk-local [bc][T][64]
{
  const int job  = blockIdx.x;
  const int b    = job >> 1;
  const int dir  = job & 1;
  const int lane = threadIdx.x;
  const int j    = lane & 31;
  const int half = lane >> 5;

  const float* Wih = dir ? Wih_b : Wih_f;
  const float* Whh = dir ? Whh_b : Whh_f;
  const float* bih = dir ? bih_b : bih_f;
  const float* bhh = dir ? bhh_b : bhh_f;

  const int mrow = half * 32 + j;   // r-row (half0) or z-row (half1)
  const int nrow = 64 + j;          // n-row

  double wh_m[32], wh_n[32];        // full rows
  float  wi_m[6], wi_n[6];
  {
    const float4* wm4 = (const float4*)(Whh + mrow*32);
#pragma unroll
    for (int q=0;q<8;q++){ float4 v=wm4[q];
      wh_m[4*q]=(double)v.x; wh_m[4*q+1]=(double)v.y;
      wh_m[4*q+2]=(double)v.z; wh_m[4*q+3]=(double)v.w; }
    const float4* wn4 = (const float4*)(Whh + nrow*32);
#pragma unroll
    for (int q=0;q<8;q++){ float4 v=wn4[q];
      wh_n[4*q]=(double)v.x; wh_n[4*q+1]=(double)v.y;
      wh_n[4*q+2]=(double)v.z; wh_n[4*q+3]=(double)v.w; }
#pragma unroll
    for (int i=0;i<6;i++) wi_m[i] = Wih[mrow*6+i];
#pragma unroll
    for (int i=0;i<6;i++) wi_n[i] = Wih[nrow*6+i];
  }
  const double b_m   = (double)bih[mrow] + (double)bhh[mrow];
  const double b_ihn = (double)bih[nrow];
  const double b_hhn = (double)bhh[nrow];

  __shared__ __align__(16) double hlds[32];

  double hreg[32];
#pragma unroll
  for (int k=0;k<32;k++) hreg[k]=0.;
  double hj = 0.;

  const long t0    = dir ? (TT-1) : 0;
  const long tstep = dir ? -1 : 1;
  const float* xrow = x + ((size_t)b*TT + t0)*6;
  const long  xinc = tstep*6;
  float* hout = h0 + ((size_t)b*TT + t0)*64 + dir*32;
  const long hinc = tstep*64;

#define L0_STEP(XV)                                                          \
  {                                                                          \
    float sx = 0.f, sxn = 0.f;                                               \
    _Pragma("unroll")                                                        \
    for (int i=0;i<6;i++){ sx  = fmaf(wi_m[i], XV[i], sx);                   \
                           sxn = fmaf(wi_n[i], XV[i], sxn); }                \
    double a0=0.,a1=0.,a2=0.,a3=0., c0=0.,c1=0.,c2=0.,c3=0.;                 \
    _Pragma("unroll")                                                        \
    for (int k=0;k<8;k++){                                                   \
      a0 = fma(wh_m[4*k+0], hreg[4*k+0], a0);                                \
      a1 = fma(wh_m[4*k+1], hreg[4*k+1], a1);                                \
      a2 = fma(wh_m[4*k+2], hreg[4*k+2], a2);                                \
      a3 = fma(wh_m[4*k+3], hreg[4*k+3], a3);                                \
      c0 = fma(wh_n[4*k+0], hreg[4*k+0], c0);                                \
      c1 = fma(wh_n[4*k+1], hreg[4*k+1], c1);                                \
      c2 = fma(wh_n[4*k+2], hreg[4*k+2], c2);                                \
      c3 = fma(wh_n[4*k+3], hreg[4*k+3], c3);                                \
    }                                                                        \
    double hm   = (a0+a1)+(a2+a3);                                           \
    double sn_h = (c0+c1)+(c2+c3);                                           \
    double vm   = hm + (double)sx + b_m;                                     \
    float  vf   = (float)vm;                                                 \
    float  varg = half ? -vf : vf;                                           \
    float  ef   = __builtin_amdgcn_exp2f(varg * -1.44269504088896341f);      \
    float  gmf  = __builtin_amdgcn_rcpf(1.f + ef);                           \
    float  wf   = __shfl_xor(gmf, 32, 64);                                   \
    double xn = (double)sxn + b_ihn;                                         \
    double hn = sn_h + b_hhn;                                                \
    float  af = (float)fma((double)gmf, hn, xn);                             \
    float  e2 = __builtin_amdgcn_exp2f(af * 2.88539008177792682f);           \
    float  nnf= 1.f - 2.f*__builtin_amdgcn_rcpf(1.f + e2);                   \
    double hnew = fma((double)wf, (double)nnf - hj, hj);                     \
    hj = hnew;                                                               \
    if (lane < 32){ hlds[j] = hnew; hout[j] = (float)hnew; }                 \
    hout += hinc;                                                            \
    {                                                                        \
      const double2* h2 = (const double2*)hlds;                              \
      _Pragma("unroll")                                                      \
      for (int q=0;q<16;q++){ double2 v=h2[q];                               \
        hreg[2*q]=v.x; hreg[2*q+1]=v.y; }                                    \
    }                                                                        \
  }

  float xa[6], xb[6];
  {
    const float2* p=(const float2*)xrow;
    xa[0]=p[0].x; xa[1]=p[0].y; xa[2]=p[1].x; xa[3]=p[1].y; xa[4]=p[2].x; xa[5]=p[2].y;
    const float2* q=(const float2*)(xrow + xinc);
    xb[0]=q[0].x; xb[1]=q[0].y; xb[2]=q[1].x; xb[3]=q[1].y; xb[4]=q[2].x; xb[5]=q[2].y;
  }
  const float* xld = xrow + 2*xinc;

#pragma unroll 1
  for (int it=0; it<TT; it+=2){
    L0_STEP(xa)
    if (it+2 < TT){
      const float2* p=(const float2*)xld;
      xa[0]=p[0].x; xa[1]=p[0].y; xa[2]=p[1].x; xa[3]=p[1].y; xa[4]=p[2].x; xa[5]=p[2].y;
      xld += xinc;
    }
    L0_STEP(xb)
    if (it+3 < TT){
      const float2* p=(const float2*)xld;
      xb[0]=p[0].x; xb[1]=p[0].y; xb[2]=p[1].x; xb[3]=p[1].y; xb[4]=p[2].x; xb[5]=p[2].y;
      xld += xinc;
    }
  }
#undef L0_STEP
}

// ---------------- Layer 1: fused input-GEMM (K=64, regs) + GRU scan + mean ----------------
// Input weights in REGISTERS (r6's LDS copy had an 8-way bank conflict on
// every read). Ring row streamed once (16 b128 broadcast reads) feeding both
// the m-dot and both-halves n-dot (select by half: each lane's wi_n slice is
// its own half's weights, so the select is exact). h readback streamed from
// LDS directly into the fp64 FMAs.

__global__ __launch_bounds__(64,1)
void gru_l1(const float* __restrict__ h0,         // chunk-local [bc][T][64]
            const float* __restrict__ Wih_f, const float* __restrict__ Whh_f,
            const float* __restrict__ bih_f, const float* __restrict__ bhh_f,
            const float* __restrict__ Wih_b, const float* __restrict__ Whh_b,
            const float* __restrict__ bih_b, const float* __restrict__ bhh_b,
            float* __restrict__ pooled)           // already offset to chunk base
{
  const int job  = blockIdx.x;
  const int b    = job >> 1;
  const int dir  = job & 1;
  const int lane = threadIdx.x;
  const int j    = lane & 31;
  const int half = lane >> 5;

  const float* Wih = dir ? Wih_b : Wih_f;
  const float* Whh = dir ? Whh_b : Whh_f;
  const float* bih = dir ? bih_b : bih_f;
  const float* bhh = dir ? bhh_b : bhh_f;

  const int mrow = half * 32 + j;
  const int nrow = 64 + j;

  float  wi_m[64], wi_n[32];
  double wh_m[32], wh_n[16];
  {
    const float4* wm4 = (const float4*)(Wih + mrow*64);
#pragma unroll
    for (int q=0;q<16;q++){ float4 v=wm4[q];
      wi_m[4*q]=v.x; wi_m[4*q+1]=v.y; wi_m[4*q+2]=v.z; wi_m[4*q+3]=v.w; }
    const float4* wn4 = (const float4*)(Wih + nrow*64 + half*32);
#pragma unroll
    for (int q=0;q<8;q++){ float4 v=wn4[q];
      wi_n[4*q]=v.x; wi_n[4*q+1]=v.y; wi_n[4*q+2]=v.z; wi_n[4*q+3]=v.w; }
    const float4* hm4 = (const float4*)(Whh + mrow*32);
#pragma unroll
    for (int q=0;q<8;q++){ float4 v=hm4[q];
      wh_m[4*q]=(double)v.x; wh_m[4*q+1]=(double)v.y;
      wh_m[4*q+2]=(double)v.z; wh_m[4*q+3]=(double)v.w; }
    const float4* hn4 = (const float4*)(Whh + nrow*32 + half*16);
#pragma unroll
    for (int q=0;q<4;q++){ float4 v=hn4[q];
      wh_n[4*q]=(double)v.x; wh_n[4*q+1]=(double)v.y;
      wh_n[4*q+2]=(double)v.z; wh_n[4*q+3]=(double)v.w; }
  }
  const double b_m   = (double)bih[mrow] + (double)bhh[mrow];
  const double b_ihn = (double)bih[nrow];
  const double b_hhn = (double)bhh[nrow];

  __shared__ __align__(16) double hlds[32];
  __shared__ __align__(16) float  ring[4*64];

  double hj = 0.;
  double psum = 0.;

  // zero-init hlds (h starts at 0)
  if (lane < 32) hlds[lane] = 0.;

  const float* h0b = h0 + (size_t)b*TT*64;

#define L1_STEP(S)                                                           \
  {                                                                          \
    const float4* s4 = (const float4*)(ring + (S)*64);                       \
    float m0=0.f,m1=0.f,m2=0.f,m3=0.f;                                       \
    float nA=0.f,nB=0.f;                                                     \
    _Pragma("unroll")                                                        \
    for (int q=0;q<16;q++){ float4 v=s4[q];                                  \
      m0=fmaf(wi_m[4*q+0],v.x,m0); m1=fmaf(wi_m[4*q+1],v.y,m1);              \
      m2=fmaf(wi_m[4*q+2],v.z,m2); m3=fmaf(wi_m[4*q+3],v.w,m3);              \
      if (q<8){  nA=fmaf(wi_n[4*q+0],v.x,nA); nA=fmaf(wi_n[4*q+1],v.y,nA);   \
                 nA=fmaf(wi_n[4*q+2],v.z,nA); nA=fmaf(wi_n[4*q+3],v.w,nA); } \
      else {     int kq=4*(q-8);                                             \
                 nB=fmaf(wi_n[kq+0],v.x,nB); nB=fmaf(wi_n[kq+1],v.y,nB);     \
                 nB=fmaf(wi_n[kq+2],v.z,nB); nB=fmaf(wi_n[kq+3],v.w,nB); }   \
    }                                                                        \
    float sx   = (m0+m1)+(m2+m3);                                            \
    float sn_x = half ? nB : nA;                                             \
    double a0=0.,a1=0.,a2=0.,a3=0.;                                          \
    {                                                                        \
      const double2* h2 = (const double2*)hlds;                              \
      _Pragma("unroll")                                                      \
      for (int q=0;q<8;q++){                                                 \
        double2 u=h2[2*q], w=h2[2*q+1];                                      \
        a0 = fma(wh_m[4*q+0], u.x, a0);                                      \
        a1 = fma(wh_m[4*q+1], u.y, a1);                                      \
        a2 = fma(wh_m[4*q+2], w.x, a2);                                      \
        a3 = fma(wh_m[4*q+3], w.y, a3);                                      \
      }                                                                      \
    }                                                                        \
    double c0=0.,c1=0.;                                                      \
    {                                                                        \
      const double2* hx2 = (const double2*)(hlds + half*16);                 \
      _Pragma("unroll")                                                      \
      for (int q=0;q<8;q++){ double2 v=hx2[q];                               \
        c0 = fma(wh_n[2*q+0], v.x, c0);                                      \
        c1 = fma(wh_n[2*q+1], v.y, c1); }                                    \
    }                                                                        \
    double hm   = (a0+a1)+(a2+a3);                                           \
    double sn_h = c0+c1;                                                     \
    double vm   = hm + (double)sx + b_m;                                     \
    float  vf   = (float)vm;                                                 \
    float  varg = half ? -vf : vf;                                           \
    float  ef   = __builtin_amdgcn_exp2f(varg * -1.44269504088896341f);      \
    float  gmf  = __builtin_amdgcn_rcpf(1.f + ef);                           \
    float  wf   = __shfl_xor(gmf,  32, 64);                                  \
    float  xn_o = __shfl_xor(sn_x, 32, 64);                                  \
    float  snhf = (float)sn_h;                                               \
    float  hn_o = __shfl_xor(snhf, 32, 64);                                  \
    double xn = (double)sn_x + (double)xn_o + b_ihn;                         \
    double hn = sn_h + (double)hn_o + b_hhn;                                 \
    float  af = (float)fma((double)gmf, hn, xn);                             \
    float  e2 = __builtin_amdgcn_exp2f(af * 2.88539008177792682f);           \
    float  nnf= 1.f - 2.f*__builtin_amdgcn_rcpf(1.f + e2);                   \
    double hnew = fma((double)wf, (double)nnf - hj, hj);                     \
    hj = hnew;                                                               \
    psum += hnew;                                                            \
    if (lane < 32) hlds[j] = hnew;                                           \
  }

  // prologue: stage rows 0..2 into slots 0..2; rows 3,4 in flight in sA,sB
  {
    const float* p0 = h0b + (size_t)(dir ? (TT-1-0) : 0)*64;
    const float* p1 = h0b + (size_t)(dir ? (TT-1-1) : 1)*64;
    const float* p2 = h0b + (size_t)(dir ? (TT-1-2) : 2)*64;
    float r0 = p0[lane], r1 = p1[lane], r2 = p2[lane];
    ring[0*64+lane]=r0; ring[1*64+lane]=r1; ring[2*64+lane]=r2;
  }
  float sA, sB;
  { const float* p = h0b + (size_t)(dir ? (TT-1-3) : 3)*64; sA = p[lane]; }
  { const float* p = h0b + (size_t)(dir ? (TT-1-4) : 4)*64; sB = p[lane]; }

#pragma unroll 1
  for (int it=0; it<TT; it+=2){
    L1_STEP(it & 3)
    ring[((it+3)&3)*64 + lane] = sA;                 // row it+3 becomes visible
    { int lt = it+5; if (lt > TT-1) lt = TT-1;
      const float* p = h0b + (size_t)(dir ? (TT-1-lt) : lt)*64; sA = p[lane]; }
    L1_STEP((it+1) & 3)
    ring[((it+4)&3)*64 + lane] = sB;                 // row it+4
    { int lt = it+6; if (lt > TT-1) lt = TT-1;
      const float* p = h0b + (size_t)(dir ? (TT-1-lt) : lt)*64; sB = p[lane]; }
  }
#undef L1_STEP

  if (lane < 32) pooled[(size_t)b*64 + dir*32 + j] = (float)psum;
}

// ---------------- FC head: mean -> fc1(relu) -> fc2 ----------------
__global__ void fc_ep(const float* __restrict__ pooled,
                      const float* __restrict__ fc1w, const float* __restrict__ fc1b,
                      const float* __restrict__ fc2w, const float* __restrict__ fc2b,
                      float* __restrict__ out)
{
  int b = blockIdx.x*blockDim.x + threadIdx.x;
  if (b >= TB) return;
  float v[64];
  const float4* p4 = (const float4*)(pooled + (size_t)b*64);
#pragma unroll
  for (int q=0;q<16;q++){ float4 t=p4[q];
    v[4*q]  =t.x*(1.f/TT); v[4*q+1]=t.y*(1.f/TT);
    v[4*q+2]=t.z*(1.f/TT); v[4*q+3]=t.w*(1.f/TT); }
  float acc = fc2b[0];
#pragma unroll
  for (int g=0; g<16; g++){
    float s = fc1b[g];
    const float4* w4 = (const float4*)(fc1w + g*64);
#pragma unroll
    for (int q=0;q<16;q++){ float4 w=w4[q];
      s=fmaf(w.x,v[4*q],s);   s=fmaf(w.y,v[4*q+1],s);
      s=fmaf(w.z,v[4*q+2],s); s=fmaf(w.w,v[4*q+3],s); }
    s = fmaxf(s, 0.f);
    acc = fmaf(fc2w[g], s, acc);
  }
  out[b] = acc;
}

extern "C" void kernel_launch(void* const* d_in, const int* in_sizes, int n_in,
                              void* d_out, int out_size, void* d_ws, size_t ws_size,
                              hipStream_t stream)
{
  (void)in_sizes; (void)n_in; (void)out_size;

  const float* x     = (const float*)d_in[0];
  const float* Wih0f = (const float*)d_in[1];
  const float* Whh0f = (const float*)d_in[2];
  const float* bih0f = (const float*)d_in[3];
  const float* bhh0f = (const float*)d_in[4];
  const float* Wih0b = (const float*)d_in[5];
  const float* Whh0b = (const float*)d_in[6];
  const float* bih0b = (const float*)d_in[7];
  const float* bhh0b = (const float*)d_in[8];
  const float* Wih1f = (const float*)d_in[9];
  const float* Whh1f = (const float*)d_in[10];
  const float* bih1f = (const float*)d_in[11];
  const float* bhh1f = (const float*)d_in[12];
  const float* Wih1b = (const float*)d_in[13];
  const float* Whh1b = (const float*)d_in[14];
  const float* bih1b = (const float*)d_in[15];
  const float* bhh1b = (const float*)d_in[16];
  const float* fc1w  = (const float*)d_in[17];
  const float* fc1b  = (const float*)d_in[18];
  const float* fc2w  = (const float*)d_in[19];
  const float* fc2b  = (const float*)d_in[20];

  // Workspace: pooled [TB][64] fp32 at front, then the chunked h0 region.
  const size_t POOLED_BYTES = (size_t)TB * 64 * sizeof(float);     // 128 KiB
  const size_t PER_B        = (size_t)TT * 64 * sizeof(float);     // 512 KiB
  float* pooled = (float*)d_ws;
  float* h0     = (float*)((char*)d_ws + POOLED_BYTES);

  size_t avail = (ws_size > POOLED_BYTES) ? (ws_size - POOLED_BYTES) : 0;
  int Bc = (int)(avail / PER_B);
  if (Bc < 1)  Bc = 1;
  if (Bc > TB) Bc = TB;
  int nch = (TB + Bc - 1) / Bc;
  int Bce = (TB + nch - 1) / nch;

  for (int b0 = 0; b0 < TB; b0 += Bce) {
    int bc = (TB - b0 < Bce) ? (TB - b0) : Bce;
    hipLaunchKernelGGL(gru_l0, dim3(2*bc), dim3(64), 0, stream,
                       x + (size_t)b0*TT*6,
                       Wih0f,Whh0f,bih0f,bhh0f, Wih0b,Whh0b,bih0b,bhh0b, h0);
    hipLaunchKernelGGL(gru_l1, dim3(2*bc), dim3(64), 0, stream,
                       h0,
                       Wih1f,Whh1f,bih1f,bhh1f, Wih1b,Whh1b,bih1b,bhh1b,
                       pooled + (size_t)b0*64);
  }
  hipLaunchKernelGGL(fc_ep, dim3(2), dim3(256), 0, stream,
                     pooled, fc1w, fc1b, fc2w, fc2b, (float*)d_out);
}

// Round 8
// 2636.510 us; speedup vs baseline: 4.0640x; 1.8165x over previous
//
#include <hip/hip_runtime.h>

#define TB  512
#define TT  2048
#define HID 32

typedef _Float16 f16;

// Numeric scheme (proven r5-r7: absmax 0.0): h-state, h-dots, update in fp64;
// gate transcendentals in fp32 hw exp2/rcp; input-path dots fp32.
// w = 1-z = sigma(-v) stable form; h' = h + w*(n-h).
// NEW r8: h0 inter-layer buffer stored fp16 (|h|<=1; errors enter only the
// non-recurrent input path of l1) -> 128 MiB -> single chunk -> full-batch
// launches (1024 waves = 1/SIMD) instead of 2 serialized half-machine chunks.

// ---------------- Layer 0: fused input-GEMM (K=6, fp32) + GRU scan ----------------
__global__ __launch_bounds__(64,1)
void gru_l0(const float* __restrict__ x,
            const float* __restrict__ Wih_f, const float* __restrict__ Whh_f,
            const float* __restrict__ bih_f, const float* __restrict__ bhh_f,
            const float* __restrict__ Wih_b, const float* __restrict__ Whh_b,
            const float* __restrict__ bih_b, const float* __restrict__ bhh_b,
            f16* __restrict__ h0)                 // chunk-local [bc][T][64] fp16
{
  const int job  = blockIdx.x;
  const int b    = job >> 1;
  const int dir  = job & 1;
  const int lane = threadIdx.x;
  const int j    = lane & 31;
  const int half = lane >> 5;

  const float* Wih = dir ? Wih_b : Wih_f;
  const float* Whh = dir ? Whh_b : Whh_f;
  const float* bih = dir ? bih_b : bih_f;
  const float* bhh = dir ? bhh_b : bhh_f;

  const int mrow = half * 32 + j;   // r-row (half0) or z-row (half1)
  const int nrow = 64 + j;          // n-row

  double wh_m[32], wh_n[32];        // full rows
  float  wi_m[6], wi_n[6];
  {
    const float4* wm4 = (const float4*)(Whh + mrow*32);
#pragma unroll
    for (int q=0;q<8;q++){ float4 v=wm4[q];
      wh_m[4*q]=(double)v.x; wh_m[4*q+1]=(double)v.y;
      wh_m[4*q+2]=(double)v.z; wh_m[4*q+3]=(double)v.w; }
    const float4* wn4 = (const float4*)(Whh + nrow*32);
#pragma unroll
    for (int q=0;q<8;q++){ float4 v=wn4[q];
      wh_n[4*q]=(double)v.x; wh_n[4*q+1]=(double)v.y;
      wh_n[4*q+2]=(double)v.z; wh_n[4*q+3]=(double)v.w; }
#pragma unroll
    for (int i=0;i<6;i++) wi_m[i] = Wih[mrow*6+i];
#pragma unroll
    for (int i=0;i<6;i++) wi_n[i] = Wih[nrow*6+i];
  }
  const double b_m   = (double)bih[mrow] + (double)bhh[mrow];
  const double b_ihn = (double)bih[nrow];
  const double b_hhn = (double)bhh[nrow];

  __shared__ __align__(16) double hlds[32];

  double hreg[32];
#pragma unroll
  for (int k=0;k<32;k++) hreg[k]=0.;
  double hj = 0.;

  const long t0    = dir ? (TT-1) : 0;
  const long tstep = dir ? -1 : 1;
  const float* xrow = x + ((size_t)b*TT + t0)*6;
  const long  xinc = tstep*6;
  f16* hout = h0 + ((size_t)b*TT + t0)*64 + dir*32;
  const long hinc = tstep*64;

#define L0_STEP(XV)                                                          \
  {                                                                          \
    float sx = 0.f, sxn = 0.f;                                               \
    _Pragma("unroll")                                                        \
    for (int i=0;i<6;i++){ sx  = fmaf(wi_m[i], XV[i], sx);                   \
                           sxn = fmaf(wi_n[i], XV[i], sxn); }                \
    double a0=0.,a1=0.,a2=0.,a3=0., c0=0.,c1=0.,c2=0.,c3=0.;                 \
    _Pragma("unroll")                                                        \
    for (int k=0;k<8;k++){                                                   \
      a0 = fma(wh_m[4*k+0], hreg[4*k+0], a0);                                \
      a1 = fma(wh_m[4*k+1], hreg[4*k+1], a1);                                \
      a2 = fma(wh_m[4*k+2], hreg[4*k+2], a2);                                \
      a3 = fma(wh_m[4*k+3], hreg[4*k+3], a3);                                \
      c0 = fma(wh_n[4*k+0], hreg[4*k+0], c0);                                \
      c1 = fma(wh_n[4*k+1], hreg[4*k+1], c1);                                \
      c2 = fma(wh_n[4*k+2], hreg[4*k+2], c2);                                \
      c3 = fma(wh_n[4*k+3], hreg[4*k+3], c3);                                \
    }                                                                        \
    double hm   = (a0+a1)+(a2+a3);                                           \
    double sn_h = (c0+c1)+(c2+c3);                                           \
    double vm   = hm + (double)sx + b_m;                                     \
    float  vf   = (float)vm;                                                 \
    float  varg = half ? -vf : vf;                                           \
    float  ef   = __builtin_amdgcn_exp2f(varg * -1.44269504088896341f);      \
    float  gmf  = __builtin_amdgcn_rcpf(1.f + ef);                           \
    float  wf   = __shfl_xor(gmf, 32, 64);                                   \
    double xn = (double)sxn + b_ihn;                                         \
    double hn = sn_h + b_hhn;                                                \
    float  af = (float)fma((double)gmf, hn, xn);                             \
    float  e2 = __builtin_amdgcn_exp2f(af * 2.88539008177792682f);           \
    float  nnf= 1.f - 2.f*__builtin_amdgcn_rcpf(1.f + e2);                   \
    double hnew = fma((double)wf, (double)nnf - hj, hj);                     \
    hj = hnew;                                                               \
    if (lane < 32){ hlds[j] = hnew; hout[j] = (f16)hnew; }                   \
    hout += hinc;                                                            \
    {                                                                        \
      const double2* h2 = (const double2*)hlds;                              \
      _Pragma("unroll")                                                      \
      for (int q=0;q<16;q++){ double2 v=h2[q];                               \
        hreg[2*q]=v.x; hreg[2*q+1]=v.y; }                                    \
    }                                                                        \
  }

  float xa[6], xb[6];
  {
    const float2* p=(const float2*)xrow;
    xa[0]=p[0].x; xa[1]=p[0].y; xa[2]=p[1].x; xa[3]=p[1].y; xa[4]=p[2].x; xa[5]=p[2].y;
    const float2* q=(const float2*)(xrow + xinc);
    xb[0]=q[0].x; xb[1]=q[0].y; xb[2]=q[1].x; xb[3]=q[1].y; xb[4]=q[2].x; xb[5]=q[2].y;
  }
  const float* xld = xrow + 2*xinc;

#pragma unroll 1
  for (int it=0; it<TT; it+=2){
    L0_STEP(xa)
    if (it+2 < TT){
      const float2* p=(const float2*)xld;
      xa[0]=p[0].x; xa[1]=p[0].y; xa[2]=p[1].x; xa[3]=p[1].y; xa[4]=p[2].x; xa[5]=p[2].y;
      xld += xinc;
    }
    L0_STEP(xb)
    if (it+3 < TT){
      const float2* p=(const float2*)xld;
      xb[0]=p[0].x; xb[1]=p[0].y; xb[2]=p[1].x; xb[3]=p[1].y; xb[4]=p[2].x; xb[5]=p[2].y;
      xld += xinc;
    }
  }
#undef L0_STEP
}

// ---------------- Layer 1: fused input-GEMM (K=64, regs) + GRU scan + mean ----------------
// Both steps' input dots (h-independent) hoisted ABOVE the serial gate chains
// so their ring reads + 128 fp32 FMAs overlap the fp64/LDS critical path.

__global__ __launch_bounds__(64,1)
void gru_l1(const f16* __restrict__ h0,           // chunk-local [bc][T][64] fp16
            const float* __restrict__ Wih_f, const float* __restrict__ Whh_f,
            const float* __restrict__ bih_f, const float* __restrict__ bhh_f,
            const float* __restrict__ Wih_b, const float* __restrict__ Whh_b,
            const float* __restrict__ bih_b, const float* __restrict__ bhh_b,
            float* __restrict__ pooled)           // already offset to chunk base
{
  const int job  = blockIdx.x;
  const int b    = job >> 1;
  const int dir  = job & 1;
  const int lane = threadIdx.x;
  const int j    = lane & 31;
  const int half = lane >> 5;

  const float* Wih = dir ? Wih_b : Wih_f;
  const float* Whh = dir ? Whh_b : Whh_f;
  const float* bih = dir ? bih_b : bih_f;
  const float* bhh = dir ? bhh_b : bhh_f;

  const int mrow = half * 32 + j;
  const int nrow = 64 + j;

  float  wi_m[64], wi_n[32];
  double wh_m[32], wh_n[16];
  {
    const float4* wm4 = (const float4*)(Wih + mrow*64);
#pragma unroll
    for (int q=0;q<16;q++){ float4 v=wm4[q];
      wi_m[4*q]=v.x; wi_m[4*q+1]=v.y; wi_m[4*q+2]=v.z; wi_m[4*q+3]=v.w; }
    const float4* wn4 = (const float4*)(Wih + nrow*64 + half*32);
#pragma unroll
    for (int q=0;q<8;q++){ float4 v=wn4[q];
      wi_n[4*q]=v.x; wi_n[4*q+1]=v.y; wi_n[4*q+2]=v.z; wi_n[4*q+3]=v.w; }
    const float4* hm4 = (const float4*)(Whh + mrow*32);
#pragma unroll
    for (int q=0;q<8;q++){ float4 v=hm4[q];
      wh_m[4*q]=(double)v.x; wh_m[4*q+1]=(double)v.y;
      wh_m[4*q+2]=(double)v.z; wh_m[4*q+3]=(double)v.w; }
    const float4* hn4 = (const float4*)(Whh + nrow*32 + half*16);
#pragma unroll
    for (int q=0;q<4;q++){ float4 v=hn4[q];
      wh_n[4*q]=(double)v.x; wh_n[4*q+1]=(double)v.y;
      wh_n[4*q+2]=(double)v.z; wh_n[4*q+3]=(double)v.w; }
  }
  const double b_m   = (double)bih[mrow] + (double)bhh[mrow];
  const double b_ihn = (double)bih[nrow];
  const double b_hhn = (double)bhh[nrow];

  __shared__ __align__(16) double hlds[32];
  __shared__ __align__(16) float  ring[4*64];

  double hj = 0.;
  double psum = 0.;

  if (lane < 32) hlds[lane] = 0.;

  const f16* h0b = h0 + (size_t)b*TT*64;

#define L1_DOTS(S, SX, SN)                                                   \
  {                                                                          \
    const float4* s4 = (const float4*)(ring + (S)*64);                       \
    float m0=0.f,m1=0.f,m2=0.f,m3=0.f;                                       \
    float nA=0.f,nB=0.f;                                                     \
    _Pragma("unroll")                                                        \
    for (int q=0;q<16;q++){ float4 v=s4[q];                                  \
      m0=fmaf(wi_m[4*q+0],v.x,m0); m1=fmaf(wi_m[4*q+1],v.y,m1);              \
      m2=fmaf(wi_m[4*q+2],v.z,m2); m3=fmaf(wi_m[4*q+3],v.w,m3);              \
      if (q<8){  nA=fmaf(wi_n[4*q+0],v.x,nA); nA=fmaf(wi_n[4*q+1],v.y,nA);   \
                 nA=fmaf(wi_n[4*q+2],v.z,nA); nA=fmaf(wi_n[4*q+3],v.w,nA); } \
      else {     int kq=4*(q-8);                                             \
                 nB=fmaf(wi_n[kq+0],v.x,nB); nB=fmaf(wi_n[kq+1],v.y,nB);     \
                 nB=fmaf(wi_n[kq+2],v.z,nB); nB=fmaf(wi_n[kq+3],v.w,nB); }   \
    }                                                                        \
    SX = (m0+m1)+(m2+m3);                                                    \
    SN = half ? nB : nA;                                                     \
  }

#define L1_CORE(SX, SN)                                                      \
  {                                                                          \
    double a0=0.,a1=0.,a2=0.,a3=0.;                                          \
    {                                                                        \
      const double2* h2 = (const double2*)hlds;                              \
      _Pragma("unroll")                                                      \
      for (int q=0;q<8;q++){                                                 \
        double2 u=h2[2*q], w=h2[2*q+1];                                      \
        a0 = fma(wh_m[4*q+0], u.x, a0);                                      \
        a1 = fma(wh_m[4*q+1], u.y, a1);                                      \
        a2 = fma(wh_m[4*q+2], w.x, a2);                                      \
        a3 = fma(wh_m[4*q+3], w.y, a3);                                      \
      }                                                                      \
    }                                                                        \
    double c0=0.,c1=0.;                                                      \
    {                                                                        \
      const double2* hx2 = (const double2*)(hlds + half*16);                 \
      _Pragma("unroll")                                                      \
      for (int q=0;q<8;q++){ double2 v=hx2[q];                               \
        c0 = fma(wh_n[2*q+0], v.x, c0);                                      \
        c1 = fma(wh_n[2*q+1], v.y, c1); }                                    \
    }                                                                        \
    double hm   = (a0+a1)+(a2+a3);                                           \
    double sn_h = c0+c1;                                                     \
    double vm   = hm + (double)(SX) + b_m;                                   \
    float  vf   = (float)vm;                                                 \
    float  varg = half ? -vf : vf;                                           \
    float  ef   = __builtin_amdgcn_exp2f(varg * -1.44269504088896341f);      \
    float  gmf  = __builtin_amdgcn_rcpf(1.f + ef);                           \
    float  wf   = __shfl_xor(gmf,  32, 64);                                  \
    float  xn_o = __shfl_xor(SN, 32, 64);                                    \
    float  snhf = (float)sn_h;                                               \
    float  hn_o = __shfl_xor(snhf, 32, 64);                                  \
    double xn = (double)(SN) + (double)xn_o + b_ihn;                         \
    double hn = sn_h + (double)hn_o + b_hhn;                                 \
    float  af = (float)fma((double)gmf, hn, xn);                             \
    float  e2 = __builtin_amdgcn_exp2f(af * 2.88539008177792682f);           \
    float  nnf= 1.f - 2.f*__builtin_amdgcn_rcpf(1.f + e2);                   \
    double hnew = fma((double)wf, (double)nnf - hj, hj);                     \
    hj = hnew;                                                               \
    psum += hnew;                                                            \
    if (lane < 32) hlds[j] = hnew;                                           \
  }

  // prologue: stage rows 0..2 into slots 0..2; rows 3,4 in flight in sA,sB
  {
    const f16* p0 = h0b + (size_t)(dir ? (TT-1-0) : 0)*64;
    const f16* p1 = h0b + (size_t)(dir ? (TT-1-1) : 1)*64;
    const f16* p2 = h0b + (size_t)(dir ? (TT-1-2) : 2)*64;
    float r0 = (float)p0[lane], r1 = (float)p1[lane], r2 = (float)p2[lane];
    ring[0*64+lane]=r0; ring[1*64+lane]=r1; ring[2*64+lane]=r2;
  }
  float sA, sB;
  { const f16* p = h0b + (size_t)(dir ? (TT-1-3) : 3)*64; sA = (float)p[lane]; }
  { const f16* p = h0b + (size_t)(dir ? (TT-1-4) : 4)*64; sB = (float)p[lane]; }

#pragma unroll 1
  for (int it=0; it<TT; it+=2){
    float sx0, sn0, sx1, sn1;
    L1_DOTS(it & 3, sx0, sn0)
    L1_DOTS((it+1) & 3, sx1, sn1)
    L1_CORE(sx0, sn0)
    ring[((it+3)&3)*64 + lane] = sA;                 // row it+3 becomes visible
    { int lt = it+5; if (lt > TT-1) lt = TT-1;
      const f16* p = h0b + (size_t)(dir ? (TT-1-lt) : lt)*64; sA = (float)p[lane]; }
    L1_CORE(sx1, sn1)
    ring[((it+4)&3)*64 + lane] = sB;                 // row it+4
    { int lt = it+6; if (lt > TT-1) lt = TT-1;
      const f16* p = h0b + (size_t)(dir ? (TT-1-lt) : lt)*64; sB = (float)p[lane]; }
  }
#undef L1_DOTS
#undef L1_CORE

  if (lane < 32) pooled[(size_t)b*64 + dir*32 + j] = (float)psum;
}

// ---------------- FC head: mean -> fc1(relu) -> fc2 ----------------
__global__ void fc_ep(const float* __restrict__ pooled,
                      const float* __restrict__ fc1w, const float* __restrict__ fc1b,
                      const float* __restrict__ fc2w, const float* __restrict__ fc2b,
                      float* __restrict__ out)
{
  int b = blockIdx.x*blockDim.x + threadIdx.x;
  if (b >= TB) return;
  float v[64];
  const float4* p4 = (const float4*)(pooled + (size_t)b*64);
#pragma unroll
  for (int q=0;q<16;q++){ float4 t=p4[q];
    v[4*q]  =t.x*(1.f/TT); v[4*q+1]=t.y*(1.f/TT);
    v[4*q+2]=t.z*(1.f/TT); v[4*q+3]=t.w*(1.f/TT); }
  float acc = fc2b[0];
#pragma unroll
  for (int g=0; g<16; g++){
    float s = fc1b[g];
    const float4* w4 = (const float4*)(fc1w + g*64);
#pragma unroll
    for (int q=0;q<16;q++){ float4 w=w4[q];
      s=fmaf(w.x,v[4*q],s);   s=fmaf(w.y,v[4*q+1],s);
      s=fmaf(w.z,v[4*q+2],s); s=fmaf(w.w,v[4*q+3],s); }
    s = fmaxf(s, 0.f);
    acc = fmaf(fc2w[g], s, acc);
  }
  out[b] = acc;
}

extern "C" void kernel_launch(void* const* d_in, const int* in_sizes, int n_in,
                              void* d_out, int out_size, void* d_ws, size_t ws_size,
                              hipStream_t stream)
{
  (void)in_sizes; (void)n_in; (void)out_size;

  const float* x     = (const float*)d_in[0];
  const float* Wih0f = (const float*)d_in[1];
  const float* Whh0f = (const float*)d_in[2];
  const float* bih0f = (const float*)d_in[3];
  const float* bhh0f = (const float*)d_in[4];
  const float* Wih0b = (const float*)d_in[5];
  const float* Whh0b = (const float*)d_in[6];
  const float* bih0b = (const float*)d_in[7];
  const float* bhh0b = (const float*)d_in[8];
  const float* Wih1f = (const float*)d_in[9];
  const float* Whh1f = (const float*)d_in[10];
  const float* bih1f = (const float*)d_in[11];
  const float* bhh1f = (const float*)d_in[12];
  const float* Wih1b = (const float*)d_in[13];
  const float* Whh1b = (const float*)d_in[14];
  const float* bih1b = (const float*)d_in[15];
  const float* bhh1b = (const float*)d_in[16];
  const float* fc1w  = (const float*)d_in[17];
  const float* fc1b  = (const float*)d_in[18];
  const float* fc2w  = (const float*)d_in[19];
  const float* fc2b  = (const float*)d_in[20];

  // Workspace: pooled [TB][64] fp32 at front, then the h0 region (fp16).
  // fp16 halves h0 to 128 MiB -> fits observed ws in ONE chunk (full-batch
  // launches, 1024 waves). Chunk loop kept for robustness.
  const size_t POOLED_BYTES = (size_t)TB * 64 * sizeof(float);     // 128 KiB
  const size_t PER_B        = (size_t)TT * 64 * sizeof(f16);       // 256 KiB
  float* pooled = (float*)d_ws;
  f16*   h0     = (f16*)((char*)d_ws + POOLED_BYTES);

  size_t avail = (ws_size > POOLED_BYTES) ? (ws_size - POOLED_BYTES) : 0;
  int Bc = (int)(avail / PER_B);
  if (Bc < 1)  Bc = 1;
  if (Bc > TB) Bc = TB;
  int nch = (TB + Bc - 1) / Bc;
  int Bce = (TB + nch - 1) / nch;

  for (int b0 = 0; b0 < TB; b0 += Bce) {
    int bc = (TB - b0 < Bce) ? (TB - b0) : Bce;
    hipLaunchKernelGGL(gru_l0, dim3(2*bc), dim3(64), 0, stream,
                       x + (size_t)b0*TT*6,
                       Wih0f,Whh0f,bih0f,bhh0f, Wih0b,Whh0b,bih0b,bhh0b, h0);
    hipLaunchKernelGGL(gru_l1, dim3(2*bc), dim3(64), 0, stream,
                       h0,
                       Wih1f,Whh1f,bih1f,bhh1f, Wih1b,Whh1b,bih1b,bhh1b,
                       pooled + (size_t)b0*64);
  }
  hipLaunchKernelGGL(fc_ep, dim3(2), dim3(256), 0, stream,
                     pooled, fc1w, fc1b, fc2w, fc2b, (float*)d_out);
}

// Round 9
// 2303.018 us; speedup vs baseline: 4.6525x; 1.1448x over previous
//
#include <hip/hip_runtime.h>

#define TB  512
#define TT  2048
#define HID 32

typedef _Float16 f16;

// Numeric scheme (r5-r8 ladder): ONLY the h-state (hj), the update fma, and
// the pool sum are fp64 — that is where fp32's ulp(h) per-step rounding
// accumulates coherently x2048 (the 6.1e-4 failure class). Dots and gates are
// fp32: their ~1e-6 errors are randomized by time-varying inputs and enter
// through damped channels (x wf for integrators, contraction for fast units).
// h0 inter-layer buffer fp16 (128 MiB -> single chunk; adds ~1.2e-4, proven r8).
// w = 1-z = sigma(-v) stable form; h' = h + w*(n-h).

// ---------------- Layer 0: fused input-GEMM (K=6) + GRU scan ----------------
// One wave per (batch,dir). Lane pair (j, j+32): lane j r-gate row, lane j+32
// z-gate row; both halves compute the full n-row dot (full-row weights in
// regs) so only the gate-value shuffle (wf) crosses halves.
__global__ __launch_bounds__(64,1)
void gru_l0(const float* __restrict__ x,
            const float* __restrict__ Wih_f, const float* __restrict__ Whh_f,
            const float* __restrict__ bih_f, const float* __restrict__ bhh_f,
            const float* __restrict__ Wih_b, const float* __restrict__ Whh_b,
            const float* __restrict__ bih_b, const float* __restrict__ bhh_b,
            f16* __restrict__ h0)                 // chunk-local [bc][T][64] fp16
{
  const int job  = blockIdx.x;
  const int b    = job >> 1;
  const int dir  = job & 1;
  const int lane = threadIdx.x;
  const int j    = lane & 31;
  const int half = lane >> 5;

  const float* Wih = dir ? Wih_b : Wih_f;
  const float* Whh = dir ? Whh_b : Whh_f;
  const float* bih = dir ? bih_b : bih_f;
  const float* bhh = dir ? bhh_b : bhh_f;

  const int mrow = half * 32 + j;   // r-row (half0) or z-row (half1)
  const int nrow = 64 + j;          // n-row

  float wh_m[32], wh_n[32];         // full rows, fp32
  float wi_m[6],  wi_n[6];
  {
    const float4* wm4 = (const float4*)(Whh + mrow*32);
#pragma unroll
    for (int q=0;q<8;q++){ float4 v=wm4[q];
      wh_m[4*q]=v.x; wh_m[4*q+1]=v.y; wh_m[4*q+2]=v.z; wh_m[4*q+3]=v.w; }
    const float4* wn4 = (const float4*)(Whh + nrow*32);
#pragma unroll
    for (int q=0;q<8;q++){ float4 v=wn4[q];
      wh_n[4*q]=v.x; wh_n[4*q+1]=v.y; wh_n[4*q+2]=v.z; wh_n[4*q+3]=v.w; }
#pragma unroll
    for (int i=0;i<6;i++) wi_m[i] = Wih[mrow*6+i];
#pragma unroll
    for (int i=0;i<6;i++) wi_n[i] = Wih[nrow*6+i];
  }
  const float b_m   = bih[mrow] + bhh[mrow];
  const float b_ihn = bih[nrow];
  const float b_hhn = bhh[nrow];

  __shared__ __align__(16) float hlds[32];

  float hreg[32];
#pragma unroll
  for (int k=0;k<32;k++) hreg[k]=0.f;
  double hj = 0.;

  const long t0    = dir ? (TT-1) : 0;
  const long tstep = dir ? -1 : 1;
  const float* xrow = x + ((size_t)b*TT + t0)*6;
  const long  xinc = tstep*6;
  f16* hout = h0 + ((size_t)b*TT + t0)*64 + dir*32;
  const long hinc = tstep*64;

#define L0_STEP(XV)                                                          \
  {                                                                          \
    float sx = 0.f, sxn = 0.f;                                               \
    _Pragma("unroll")                                                        \
    for (int i=0;i<6;i++){ sx  = fmaf(wi_m[i], XV[i], sx);                   \
                           sxn = fmaf(wi_n[i], XV[i], sxn); }                \
    float a0=0.f,a1=0.f,a2=0.f,a3=0.f, c0=0.f,c1=0.f,c2=0.f,c3=0.f;          \
    _Pragma("unroll")                                                        \
    for (int k=0;k<8;k++){                                                   \
      a0 = fmaf(wh_m[4*k+0], hreg[4*k+0], a0);                               \
      a1 = fmaf(wh_m[4*k+1], hreg[4*k+1], a1);                               \
      a2 = fmaf(wh_m[4*k+2], hreg[4*k+2], a2);                               \
      a3 = fmaf(wh_m[4*k+3], hreg[4*k+3], a3);                               \
      c0 = fmaf(wh_n[4*k+0], hreg[4*k+0], c0);                               \
      c1 = fmaf(wh_n[4*k+1], hreg[4*k+1], c1);                               \
      c2 = fmaf(wh_n[4*k+2], hreg[4*k+2], c2);                               \
      c3 = fmaf(wh_n[4*k+3], hreg[4*k+3], c3);                               \
    }                                                                        \
    float hm   = (a0+a1)+(a2+a3);                                            \
    float sn_h = (c0+c1)+(c2+c3);                                            \
    float vf   = hm + sx + b_m;                                              \
    float varg = half ? -vf : vf;                                            \
    float ef   = __builtin_amdgcn_exp2f(varg * -1.44269504088896341f);       \
    float gmf  = __builtin_amdgcn_rcpf(1.f + ef);                            \
    float wf   = __shfl_xor(gmf, 32, 64);                                    \
    float xn = sxn + b_ihn;                                                  \
    float hn = sn_h + b_hhn;                                                 \
    float af = fmaf(gmf, hn, xn);                                            \
    float e2 = __builtin_amdgcn_exp2f(af * 2.88539008177792682f);            \
    float nnf= 1.f - 2.f*__builtin_amdgcn_rcpf(1.f + e2);                    \
    double hnew = fma((double)wf, (double)nnf - hj, hj);                     \
    hj = hnew;                                                               \
    if (lane < 32){ hlds[j] = (float)hnew; hout[j] = (f16)hnew; }            \
    hout += hinc;                                                            \
    {                                                                        \
      const float4* h4 = (const float4*)hlds;                                \
      _Pragma("unroll")                                                      \
      for (int q=0;q<8;q++){ float4 v=h4[q];                                 \
        hreg[4*q]=v.x; hreg[4*q+1]=v.y; hreg[4*q+2]=v.z; hreg[4*q+3]=v.w; }  \
    }                                                                        \
  }

  float xa[6], xb[6];
  {
    const float2* p=(const float2*)xrow;
    xa[0]=p[0].x; xa[1]=p[0].y; xa[2]=p[1].x; xa[3]=p[1].y; xa[4]=p[2].x; xa[5]=p[2].y;
    const float2* q=(const float2*)(xrow + xinc);
    xb[0]=q[0].x; xb[1]=q[0].y; xb[2]=q[1].x; xb[3]=q[1].y; xb[4]=q[2].x; xb[5]=q[2].y;
  }
  const float* xld = xrow + 2*xinc;

#pragma unroll 1
  for (int it=0; it<TT; it+=2){
    L0_STEP(xa)
    if (it+2 < TT){
      const float2* p=(const float2*)xld;
      xa[0]=p[0].x; xa[1]=p[0].y; xa[2]=p[1].x; xa[3]=p[1].y; xa[4]=p[2].x; xa[5]=p[2].y;
      xld += xinc;
    }
    L0_STEP(xb)
    if (it+3 < TT){
      const float2* p=(const float2*)xld;
      xb[0]=p[0].x; xb[1]=p[0].y; xb[2]=p[1].x; xb[3]=p[1].y; xb[4]=p[2].x; xb[5]=p[2].y;
      xld += xinc;
    }
  }
#undef L0_STEP
}

// ---------------- Layer 1: fused input-GEMM (K=64) + GRU scan + time-mean ----------------
// Input weights in regs; ring rows (fp16 h0 -> fp32) staged via LDS, broadcast
// reads; h broadcast in LDS as fp32 (m-dot reads all 32, n-dot its half).
// Both steps' input dots hoisted above the serial gate chains.
__global__ __launch_bounds__(64,1)
void gru_l1(const f16* __restrict__ h0,           // chunk-local [bc][T][64] fp16
            const float* __restrict__ Wih_f, const float* __restrict__ Whh_f,
            const float* __restrict__ bih_f, const float* __restrict__ bhh_f,
            const float* __restrict__ Wih_b, const float* __restrict__ Whh_b,
            const float* __restrict__ bih_b, const float* __restrict__ bhh_b,
            float* __restrict__ pooled)
{
  const int job  = blockIdx.x;
  const int b    = job >> 1;
  const int dir  = job & 1;
  const int lane = threadIdx.x;
  const int j    = lane & 31;
  const int half = lane >> 5;

  const float* Wih = dir ? Wih_b : Wih_f;
  const float* Whh = dir ? Whh_b : Whh_f;
  const float* bih = dir ? bih_b : bih_f;
  const float* bhh = dir ? bhh_b : bhh_f;

  const int mrow = half * 32 + j;
  const int nrow = 64 + j;

  float wi_m[64], wi_n[32];
  float wh_m[32], wh_n[16];
  {
    const float4* wm4 = (const float4*)(Wih + mrow*64);
#pragma unroll
    for (int q=0;q<16;q++){ float4 v=wm4[q];
      wi_m[4*q]=v.x; wi_m[4*q+1]=v.y; wi_m[4*q+2]=v.z; wi_m[4*q+3]=v.w; }
    const float4* wn4 = (const float4*)(Wih + nrow*64 + half*32);
#pragma unroll
    for (int q=0;q<8;q++){ float4 v=wn4[q];
      wi_n[4*q]=v.x; wi_n[4*q+1]=v.y; wi_n[4*q+2]=v.z; wi_n[4*q+3]=v.w; }
    const float4* hm4 = (const float4*)(Whh + mrow*32);
#pragma unroll
    for (int q=0;q<8;q++){ float4 v=hm4[q];
      wh_m[4*q]=v.x; wh_m[4*q+1]=v.y; wh_m[4*q+2]=v.z; wh_m[4*q+3]=v.w; }
    const float4* hn4 = (const float4*)(Whh + nrow*32 + half*16);
#pragma unroll
    for (int q=0;q<4;q++){ float4 v=hn4[q];
      wh_n[4*q]=v.x; wh_n[4*q+1]=v.y; wh_n[4*q+2]=v.z; wh_n[4*q+3]=v.w; }
  }
  const float b_m   = bih[mrow] + bhh[mrow];
  const float b_ihn = bih[nrow];
  const float b_hhn = bhh[nrow];

  __shared__ __align__(16) float hlds[32];
  __shared__ __align__(16) float ring[4*64];

  double hj = 0.;
  double psum = 0.;

  if (lane < 32) hlds[lane] = 0.f;

  const f16* h0b = h0 + (size_t)b*TT*64;

#define L1_DOTS(S, SX, SN)                                                   \
  {                                                                          \
    const float4* s4 = (const float4*)(ring + (S)*64);                       \
    float m0=0.f,m1=0.f,m2=0.f,m3=0.f;                                       \
    float nA=0.f,nB=0.f;                                                     \
    _Pragma("unroll")                                                        \
    for (int q=0;q<16;q++){ float4 v=s4[q];                                  \
      m0=fmaf(wi_m[4*q+0],v.x,m0); m1=fmaf(wi_m[4*q+1],v.y,m1);              \
      m2=fmaf(wi_m[4*q+2],v.z,m2); m3=fmaf(wi_m[4*q+3],v.w,m3);              \
      if (q<8){  nA=fmaf(wi_n[4*q+0],v.x,nA); nA=fmaf(wi_n[4*q+1],v.y,nA);   \
                 nA=fmaf(wi_n[4*q+2],v.z,nA); nA=fmaf(wi_n[4*q+3],v.w,nA); } \
      else {     int kq=4*(q-8);                                             \
                 nB=fmaf(wi_n[kq+0],v.x,nB); nB=fmaf(wi_n[kq+1],v.y,nB);     \
                 nB=fmaf(wi_n[kq+2],v.z,nB); nB=fmaf(wi_n[kq+3],v.w,nB); }   \
    }                                                                        \
    SX = (m0+m1)+(m2+m3);                                                    \
    SN = half ? nB : nA;                                                     \
  }

#define L1_CORE(SX, SN)                                                      \
  {                                                                          \
    float a0=0.f,a1=0.f,a2=0.f,a3=0.f;                                       \
    {                                                                        \
      const float4* h4 = (const float4*)hlds;                                \
      _Pragma("unroll")                                                      \
      for (int q=0;q<8;q++){ float4 v=h4[q];                                 \
        a0 = fmaf(wh_m[4*q+0], v.x, a0);                                     \
        a1 = fmaf(wh_m[4*q+1], v.y, a1);                                     \
        a2 = fmaf(wh_m[4*q+2], v.z, a2);                                     \
        a3 = fmaf(wh_m[4*q+3], v.w, a3);                                     \
      }                                                                      \
    }                                                                        \
    float c0=0.f,c1=0.f;                                                     \
    {                                                                        \
      const float4* hx4 = (const float4*)(hlds + half*16);                   \
      _Pragma("unroll")                                                      \
      for (int q=0;q<4;q++){ float4 v=hx4[q];                                \
        c0 = fmaf(wh_n[4*q+0], v.x, c0);                                     \
        c1 = fmaf(wh_n[4*q+1], v.y, c1);                                     \
        c0 = fmaf(wh_n[4*q+2], v.z, c0);                                     \
        c1 = fmaf(wh_n[4*q+3], v.w, c1); }                                   \
    }                                                                        \
    float hm   = (a0+a1)+(a2+a3);                                            \
    float sn_h = c0+c1;                                                      \
    float vf   = hm + (SX) + b_m;                                            \
    float varg = half ? -vf : vf;                                            \
    float ef   = __builtin_amdgcn_exp2f(varg * -1.44269504088896341f);       \
    float gmf  = __builtin_amdgcn_rcpf(1.f + ef);                            \
    float wf   = __shfl_xor(gmf,  32, 64);                                   \
    float xn_o = __shfl_xor(SN, 32, 64);                                     \
    float hn_o = __shfl_xor(sn_h, 32, 64);                                   \
    float xn = (SN) + xn_o + b_ihn;                                          \
    float hn = sn_h + hn_o + b_hhn;                                          \
    float af = fmaf(gmf, hn, xn);                                            \
    float e2 = __builtin_amdgcn_exp2f(af * 2.88539008177792682f);            \
    float nnf= 1.f - 2.f*__builtin_amdgcn_rcpf(1.f + e2);                    \
    double hnew = fma((double)wf, (double)nnf - hj, hj);                     \
    hj = hnew;                                                               \
    psum += hnew;                                                            \
    if (lane < 32) hlds[j] = (float)hnew;                                    \
  }

  // prologue: stage rows 0..2 into slots 0..2; rows 3,4 in flight in sA,sB
  {
    const f16* p0 = h0b + (size_t)(dir ? (TT-1-0) : 0)*64;
    const f16* p1 = h0b + (size_t)(dir ? (TT-1-1) : 1)*64;
    const f16* p2 = h0b + (size_t)(dir ? (TT-1-2) : 2)*64;
    float r0 = (float)p0[lane], r1 = (float)p1[lane], r2 = (float)p2[lane];
    ring[0*64+lane]=r0; ring[1*64+lane]=r1; ring[2*64+lane]=r2;
  }
  float sA, sB;
  { const f16* p = h0b + (size_t)(dir ? (TT-1-3) : 3)*64; sA = (float)p[lane]; }
  { const f16* p = h0b + (size_t)(dir ? (TT-1-4) : 4)*64; sB = (float)p[lane]; }

#pragma unroll 1
  for (int it=0; it<TT; it+=2){
    float sx0, sn0, sx1, sn1;
    L1_DOTS(it & 3, sx0, sn0)
    L1_DOTS((it+1) & 3, sx1, sn1)
    L1_CORE(sx0, sn0)
    ring[((it+3)&3)*64 + lane] = sA;                 // row it+3 becomes visible
    { int lt = it+5; if (lt > TT-1) lt = TT-1;
      const f16* p = h0b + (size_t)(dir ? (TT-1-lt) : lt)*64; sA = (float)p[lane]; }
    L1_CORE(sx1, sn1)
    ring[((it+4)&3)*64 + lane] = sB;                 // row it+4
    { int lt = it+6; if (lt > TT-1) lt = TT-1;
      const f16* p = h0b + (size_t)(dir ? (TT-1-lt) : lt)*64; sB = (float)p[lane]; }
  }
#undef L1_DOTS
#undef L1_CORE

  if (lane < 32) pooled[(size_t)b*64 + dir*32 + j] = (float)psum;
}

// ---------------- FC head: mean -> fc1(relu) -> fc2 ----------------
__global__ void fc_ep(const float* __restrict__ pooled,
                      const float* __restrict__ fc1w, const float* __restrict__ fc1b,
                      const float* __restrict__ fc2w, const float* __restrict__ fc2b,
                      float* __restrict__ out)
{
  int b = blockIdx.x*blockDim.x + threadIdx.x;
  if (b >= TB) return;
  float v[64];
  const float4* p4 = (const float4*)(pooled + (size_t)b*64);
#pragma unroll
  for (int q=0;q<16;q++){ float4 t=p4[q];
    v[4*q]  =t.x*(1.f/TT); v[4*q+1]=t.y*(1.f/TT);
    v[4*q+2]=t.z*(1.f/TT); v[4*q+3]=t.w*(1.f/TT); }
  float acc = fc2b[0];
#pragma unroll
  for (int g=0; g<16; g++){
    float s = fc1b[g];
    const float4* w4 = (const float4*)(fc1w + g*64);
#pragma unroll
    for (int q=0;q<16;q++){ float4 w=w4[q];
      s=fmaf(w.x,v[4*q],s);   s=fmaf(w.y,v[4*q+1],s);
      s=fmaf(w.z,v[4*q+2],s); s=fmaf(w.w,v[4*q+3],s); }
    s = fmaxf(s, 0.f);
    acc = fmaf(fc2w[g], s, acc);
  }
  out[b] = acc;
}

extern "C" void kernel_launch(void* const* d_in, const int* in_sizes, int n_in,
                              void* d_out, int out_size, void* d_ws, size_t ws_size,
                              hipStream_t stream)
{
  (void)in_sizes; (void)n_in; (void)out_size;

  const float* x     = (const float*)d_in[0];
  const float* Wih0f = (const float*)d_in[1];
  const float* Whh0f = (const float*)d_in[2];
  const float* bih0f = (const float*)d_in[3];
  const float* bhh0f = (const float*)d_in[4];
  const float* Wih0b = (const float*)d_in[5];
  const float* Whh0b = (const float*)d_in[6];
  const float* bih0b = (const float*)d_in[7];
  const float* bhh0b = (const float*)d_in[8];
  const float* Wih1f = (const float*)d_in[9];
  const float* Whh1f = (const float*)d_in[10];
  const float* bih1f = (const float*)d_in[11];
  const float* bhh1f = (const float*)d_in[12];
  const float* Wih1b = (const float*)d_in[13];
  const float* Whh1b = (const float*)d_in[14];
  const float* bih1b = (const float*)d_in[15];
  const float* bhh1b = (const float*)d_in[16];
  const float* fc1w  = (const float*)d_in[17];
  const float* fc1b  = (const float*)d_in[18];
  const float* fc2w  = (const float*)d_in[19];
  const float* fc2b  = (const float*)d_in[20];

  // Workspace: pooled [TB][64] fp32 at front, then the h0 region (fp16,
  // 128 MiB -> single chunk). Chunk loop kept for robustness.
  const size_t POOLED_BYTES = (size_t)TB * 64 * sizeof(float);     // 128 KiB
  const size_t PER_B        = (size_t)TT * 64 * sizeof(f16);       // 256 KiB
  float* pooled = (float*)d_ws;
  f16*   h0     = (f16*)((char*)d_ws + POOLED_BYTES);

  size_t avail = (ws_size > POOLED_BYTES) ? (ws_size - POOLED_BYTES) : 0;
  int Bc = (int)(avail / PER_B);
  if (Bc < 1)  Bc = 1;
  if (Bc > TB) Bc = TB;
  int nch = (TB + Bc - 1) / Bc;
  int Bce = (TB + nch - 1) / nch;

  for (int b0 = 0; b0 < TB; b0 += Bce) {
    int bc = (TB - b0 < Bce) ? (TB - b0) : Bce;
    hipLaunchKernelGGL(gru_l0, dim3(2*bc), dim3(64), 0, stream,
                       x + (size_t)b0*TT*6,
                       Wih0f,Whh0f,bih0f,bhh0f, Wih0b,Whh0b,bih0b,bhh0b, h0);
    hipLaunchKernelGGL(gru_l1, dim3(2*bc), dim3(64), 0, stream,
                       h0,
                       Wih1f,Whh1f,bih1f,bhh1f, Wih1b,Whh1b,bih1b,bhh1b,
                       pooled + (size_t)b0*64);
  }
  hipLaunchKernelGGL(fc_ep, dim3(2), dim3(256), 0, stream,
                     pooled, fc1w, fc1b, fc2w, fc2b, (float*)d_out);
}

// Round 11
// 2250.787 us; speedup vs baseline: 4.7604x; 1.0232x over previous
//
#include <hip/hip_runtime.h>

#define TB  512
#define TT  2048
#define HID 32

typedef _Float16 f16;

// Numeric scheme (r5-r9 ladder, proven): ONLY h-state (hj), the update fma,
// and the pool sum are fp64 (fp32's per-step ulp rounding there accumulates
// coherently x2048 -> the 6.1e-4 failure class). Dots and gates fp32 with hw
// exp2/rcp; h0 inter-layer buffer fp16 (single 128 MiB chunk, +1.2e-4).
// w = 1-z = sigma(-v) stable form; h' = h + w*(n-h).
//
// r11: permlane32_swap select FIXED (r10 had it inverted -> identity).
// v_permlane32_swap_b32 with both inputs = x returns:
//   r.x[l] = l<32 ? x[l]    : x[l-32]
//   r.y[l] = l<32 ? x[l+32] : x[l]
// so x[l^32] = half ? r.x : r.y.

__device__ __forceinline__ float half_swap(float x, int half){
#if __has_builtin(__builtin_amdgcn_permlane32_swap)
  typedef unsigned uv2 __attribute__((ext_vector_type(2)));
  uv2 r = __builtin_amdgcn_permlane32_swap(__float_as_uint(x), __float_as_uint(x),
                                           false, false);
  return __uint_as_float(half ? r.x : r.y);
#else
  (void)half;
  return __shfl_xor(x, 32, 64);
#endif
}

// ---------------- Layer 0: fused input-GEMM (K=6) + GRU scan ----------------
// One wave per (batch,dir). Lane pair (j, j+32): lane j r-gate row, lane j+32
// z-gate row; both halves compute the full n-row dot (full-row weights in
// regs) so only the gate value crosses halves (permlane).
__global__ __launch_bounds__(64,1)
void gru_l0(const float* __restrict__ x,
            const float* __restrict__ Wih_f, const float* __restrict__ Whh_f,
            const float* __restrict__ bih_f, const float* __restrict__ bhh_f,
            const float* __restrict__ Wih_b, const float* __restrict__ Whh_b,
            const float* __restrict__ bih_b, const float* __restrict__ bhh_b,
            f16* __restrict__ h0)                 // chunk-local [bc][T][64] fp16
{
  const int job  = blockIdx.x;
  const int b    = job >> 1;
  const int dir  = job & 1;
  const int lane = threadIdx.x;
  const int j    = lane & 31;
  const int half = lane >> 5;

  const float* Wih = dir ? Wih_b : Wih_f;
  const float* Whh = dir ? Whh_b : Whh_f;
  const float* bih = dir ? bih_b : bih_f;
  const float* bhh = dir ? bhh_b : bhh_f;

  const int mrow = half * 32 + j;   // r-row (half0) or z-row (half1)
  const int nrow = 64 + j;          // n-row

  float wh_m[32], wh_n[32];         // full rows, fp32
  float wi_m[6],  wi_n[6];
  {
    const float4* wm4 = (const float4*)(Whh + mrow*32);
#pragma unroll
    for (int q=0;q<8;q++){ float4 v=wm4[q];
      wh_m[4*q]=v.x; wh_m[4*q+1]=v.y; wh_m[4*q+2]=v.z; wh_m[4*q+3]=v.w; }
    const float4* wn4 = (const float4*)(Whh + nrow*32);
#pragma unroll
    for (int q=0;q<8;q++){ float4 v=wn4[q];
      wh_n[4*q]=v.x; wh_n[4*q+1]=v.y; wh_n[4*q+2]=v.z; wh_n[4*q+3]=v.w; }
#pragma unroll
    for (int i=0;i<6;i++) wi_m[i] = Wih[mrow*6+i];
#pragma unroll
    for (int i=0;i<6;i++) wi_n[i] = Wih[nrow*6+i];
  }
  const float b_m   = bih[mrow] + bhh[mrow];
  const float b_ihn = bih[nrow];
  const float b_hhn = bhh[nrow];

  __shared__ __align__(16) float hlds[32];

  float hreg[32];
#pragma unroll
  for (int k=0;k<32;k++) hreg[k]=0.f;
  double hj = 0.;

  const long t0    = dir ? (TT-1) : 0;
  const long tstep = dir ? -1 : 1;
  const float* xrow = x + ((size_t)b*TT + t0)*6;
  const long  xinc = tstep*6;
  f16* hout = h0 + ((size_t)b*TT + t0)*64 + dir*32;
  const long hinc = tstep*64;

#define L0_STEP(XV)                                                          \
  {                                                                          \
    float sx = 0.f, sxn = 0.f;                                               \
    _Pragma("unroll")                                                        \
    for (int i=0;i<6;i++){ sx  = fmaf(wi_m[i], XV[i], sx);                   \
                           sxn = fmaf(wi_n[i], XV[i], sxn); }                \
    float a0=0.f,a1=0.f,a2=0.f,a3=0.f, c0=0.f,c1=0.f,c2=0.f,c3=0.f;          \
    _Pragma("unroll")                                                        \
    for (int k=0;k<8;k++){                                                   \
      a0 = fmaf(wh_m[4*k+0], hreg[4*k+0], a0);                               \
      a1 = fmaf(wh_m[4*k+1], hreg[4*k+1], a1);                               \
      a2 = fmaf(wh_m[4*k+2], hreg[4*k+2], a2);                               \
      a3 = fmaf(wh_m[4*k+3], hreg[4*k+3], a3);                               \
      c0 = fmaf(wh_n[4*k+0], hreg[4*k+0], c0);                               \
      c1 = fmaf(wh_n[4*k+1], hreg[4*k+1], c1);                               \
      c2 = fmaf(wh_n[4*k+2], hreg[4*k+2], c2);                               \
      c3 = fmaf(wh_n[4*k+3], hreg[4*k+3], c3);                               \
    }                                                                        \
    float hm   = (a0+a1)+(a2+a3);                                            \
    float sn_h = (c0+c1)+(c2+c3);                                            \
    float vf   = hm + sx + b_m;                                              \
    float varg = half ? -vf : vf;                                            \
    float ef   = __builtin_amdgcn_exp2f(varg * -1.44269504088896341f);       \
    float gmf  = __builtin_amdgcn_rcpf(1.f + ef);                            \
    float wf   = half_swap(gmf, half);                                       \
    float xn = sxn + b_ihn;                                                  \
    float hn = sn_h + b_hhn;                                                 \
    float af = fmaf(gmf, hn, xn);                                            \
    float e2 = __builtin_amdgcn_exp2f(af * 2.88539008177792682f);            \
    float nnf= 1.f - 2.f*__builtin_amdgcn_rcpf(1.f + e2);                    \
    double hnew = fma((double)wf, (double)nnf - hj, hj);                     \
    hj = hnew;                                                               \
    if (lane < 32){ hlds[j] = (float)hnew; hout[j] = (f16)hnew; }            \
    hout += hinc;                                                            \
    {                                                                        \
      const float4* h4 = (const float4*)hlds;                                \
      _Pragma("unroll")                                                      \
      for (int q=0;q<8;q++){ float4 v=h4[q];                                 \
        hreg[4*q]=v.x; hreg[4*q+1]=v.y; hreg[4*q+2]=v.z; hreg[4*q+3]=v.w; }  \
    }                                                                        \
  }

  float xa[6], xb[6];
  {
    const float2* p=(const float2*)xrow;
    xa[0]=p[0].x; xa[1]=p[0].y; xa[2]=p[1].x; xa[3]=p[1].y; xa[4]=p[2].x; xa[5]=p[2].y;
    const float2* q=(const float2*)(xrow + xinc);
    xb[0]=q[0].x; xb[1]=q[0].y; xb[2]=q[1].x; xb[3]=q[1].y; xb[4]=q[2].x; xb[5]=q[2].y;
  }
  const float* xld = xrow + 2*xinc;

#pragma unroll 1
  for (int it=0; it<TT; it+=2){
    L0_STEP(xa)
    if (it+2 < TT){
      const float2* p=(const float2*)xld;
      xa[0]=p[0].x; xa[1]=p[0].y; xa[2]=p[1].x; xa[3]=p[1].y; xa[4]=p[2].x; xa[5]=p[2].y;
      xld += xinc;
    }
    L0_STEP(xb)
    if (it+3 < TT){
      const float2* p=(const float2*)xld;
      xb[0]=p[0].x; xb[1]=p[0].y; xb[2]=p[1].x; xb[3]=p[1].y; xb[4]=p[2].x; xb[5]=p[2].y;
      xld += xinc;
    }
  }
#undef L0_STEP
}

// ---------------- Layer 1: fused input-GEMM (K=64) + GRU scan + time-mean ----------------
// Input weights in regs; ring rows (fp16 h0 -> fp32) staged via LDS, broadcast
// reads; h broadcast in LDS fp32. Both steps' input dots hoisted above the
// serial gate chains; cross-half exchanges via permlane (VALU).
__global__ __launch_bounds__(64,1)
void gru_l1(const f16* __restrict__ h0,           // chunk-local [bc][T][64] fp16
            const float* __restrict__ Wih_f, const float* __restrict__ Whh_f,
            const float* __restrict__ bih_f, const float* __restrict__ bhh_f,
            const float* __restrict__ Wih_b, const float* __restrict__ Whh_b,
            const float* __restrict__ bih_b, const float* __restrict__ bhh_b,
            float* __restrict__ pooled)
{
  const int job  = blockIdx.x;
  const int b    = job >> 1;
  const int dir  = job & 1;
  const int lane = threadIdx.x;
  const int j    = lane & 31;
  const int half = lane >> 5;

  const float* Wih = dir ? Wih_b : Wih_f;
  const float* Whh = dir ? Whh_b : Whh_f;
  const float* bih = dir ? bih_b : bih_f;
  const float* bhh = dir ? bhh_b : bhh_f;

  const int mrow = half * 32 + j;
  const int nrow = 64 + j;

  float wi_m[64], wi_n[32];
  float wh_m[32], wh_n[16];
  {
    const float4* wm4 = (const float4*)(Wih + mrow*64);
#pragma unroll
    for (int q=0;q<16;q++){ float4 v=wm4[q];
      wi_m[4*q]=v.x; wi_m[4*q+1]=v.y; wi_m[4*q+2]=v.z; wi_m[4*q+3]=v.w; }
    const float4* wn4 = (const float4*)(Wih + nrow*64 + half*32);
#pragma unroll
    for (int q=0;q<8;q++){ float4 v=wn4[q];
      wi_n[4*q]=v.x; wi_n[4*q+1]=v.y; wi_n[4*q+2]=v.z; wi_n[4*q+3]=v.w; }
    const float4* hm4 = (const float4*)(Whh + mrow*32);
#pragma unroll
    for (int q=0;q<8;q++){ float4 v=hm4[q];
      wh_m[4*q]=v.x; wh_m[4*q+1]=v.y; wh_m[4*q+2]=v.z; wh_m[4*q+3]=v.w; }
    const float4* hn4 = (const float4*)(Whh + nrow*32 + half*16);
#pragma unroll
    for (int q=0;q<4;q++){ float4 v=hn4[q];
      wh_n[4*q]=v.x; wh_n[4*q+1]=v.y; wh_n[4*q+2]=v.z; wh_n[4*q+3]=v.w; }
  }
  const float b_m   = bih[mrow] + bhh[mrow];
  const float b_ihn = bih[nrow];
  const float b_hhn = bhh[nrow];

  __shared__ __align__(16) float hlds[32];
  __shared__ __align__(16) float ring[4*64];

  double hj = 0.;
  double psum = 0.;

  if (lane < 32) hlds[lane] = 0.f;

  const f16* h0b = h0 + (size_t)b*TT*64;

#define L1_DOTS(S, SX, SN)                                                   \
  {                                                                          \
    const float4* s4 = (const float4*)(ring + (S)*64);                       \
    float m0=0.f,m1=0.f,m2=0.f,m3=0.f;                                       \
    float nA=0.f,nB=0.f;                                                     \
    _Pragma("unroll")                                                        \
    for (int q=0;q<16;q++){ float4 v=s4[q];                                  \
      m0=fmaf(wi_m[4*q+0],v.x,m0); m1=fmaf(wi_m[4*q+1],v.y,m1);              \
      m2=fmaf(wi_m[4*q+2],v.z,m2); m3=fmaf(wi_m[4*q+3],v.w,m3);              \
      if (q<8){  nA=fmaf(wi_n[4*q+0],v.x,nA); nA=fmaf(wi_n[4*q+1],v.y,nA);   \
                 nA=fmaf(wi_n[4*q+2],v.z,nA); nA=fmaf(wi_n[4*q+3],v.w,nA); } \
      else {     int kq=4*(q-8);                                             \
                 nB=fmaf(wi_n[kq+0],v.x,nB); nB=fmaf(wi_n[kq+1],v.y,nB);     \
                 nB=fmaf(wi_n[kq+2],v.z,nB); nB=fmaf(wi_n[kq+3],v.w,nB); }   \
    }                                                                        \
    SX = (m0+m1)+(m2+m3);                                                    \
    SN = half ? nB : nA;                                                     \
  }

#define L1_CORE(SX, SN)                                                      \
  {                                                                          \
    float a0=0.f,a1=0.f,a2=0.f,a3=0.f;                                       \
    {                                                                        \
      const float4* h4 = (const float4*)hlds;                                \
      _Pragma("unroll")                                                      \
      for (int q=0;q<8;q++){ float4 v=h4[q];                                 \
        a0 = fmaf(wh_m[4*q+0], v.x, a0);                                     \
        a1 = fmaf(wh_m[4*q+1], v.y, a1);                                     \
        a2 = fmaf(wh_m[4*q+2], v.z, a2);                                     \
        a3 = fmaf(wh_m[4*q+3], v.w, a3);                                     \
      }                                                                      \
    }                                                                        \
    float c0=0.f,c1=0.f;                                                     \
    {                                                                        \
      const float4* hx4 = (const float4*)(hlds + half*16);                   \
      _Pragma("unroll")                                                      \
      for (int q=0;q<4;q++){ float4 v=hx4[q];                                \
        c0 = fmaf(wh_n[4*q+0], v.x, c0);                                     \
        c1 = fmaf(wh_n[4*q+1], v.y, c1);                                     \
        c0 = fmaf(wh_n[4*q+2], v.z, c0);                                     \
        c1 = fmaf(wh_n[4*q+3], v.w, c1); }                                   \
    }                                                                        \
    float hm   = (a0+a1)+(a2+a3);                                            \
    float sn_h = c0+c1;                                                      \
    float vf   = hm + (SX) + b_m;                                            \
    float varg = half ? -vf : vf;                                            \
    float ef   = __builtin_amdgcn_exp2f(varg * -1.44269504088896341f);       \
    float gmf  = __builtin_amdgcn_rcpf(1.f + ef);                            \
    float wf   = half_swap(gmf, half);                                       \
    float xn_o = half_swap(SN, half);                                        \
    float hn_o = half_swap(sn_h, half);                                      \
    float xn = (SN) + xn_o + b_ihn;                                          \
    float hn = sn_h + hn_o + b_hhn;                                          \
    float af = fmaf(gmf, hn, xn);                                            \
    float e2 = __builtin_amdgcn_exp2f(af * 2.88539008177792682f);            \
    float nnf= 1.f - 2.f*__builtin_amdgcn_rcpf(1.f + e2);                    \
    double hnew = fma((double)wf, (double)nnf - hj, hj);                     \
    hj = hnew;                                                               \
    psum += hnew;                                                            \
    if (lane < 32) hlds[j] = (float)hnew;                                    \
  }

  // prologue: stage rows 0..2 into slots 0..2; rows 3,4 in flight in sA,sB
  {
    const f16* p0 = h0b + (size_t)(dir ? (TT-1-0) : 0)*64;
    const f16* p1 = h0b + (size_t)(dir ? (TT-1-1) : 1)*64;
    const f16* p2 = h0b + (size_t)(dir ? (TT-1-2) : 2)*64;
    float r0 = (float)p0[lane], r1 = (float)p1[lane], r2 = (float)p2[lane];
    ring[0*64+lane]=r0; ring[1*64+lane]=r1; ring[2*64+lane]=r2;
  }
  float sA, sB;
  { const f16* p = h0b + (size_t)(dir ? (TT-1-3) : 3)*64; sA = (float)p[lane]; }
  { const f16* p = h0b + (size_t)(dir ? (TT-1-4) : 4)*64; sB = (float)p[lane]; }

#pragma unroll 1
  for (int it=0; it<TT; it+=2){
    float sx0, sn0, sx1, sn1;
    L1_DOTS(it & 3, sx0, sn0)
    L1_DOTS((it+1) & 3, sx1, sn1)
    L1_CORE(sx0, sn0)
    ring[((it+3)&3)*64 + lane] = sA;                 // row it+3 becomes visible
    { int lt = it+5; if (lt > TT-1) lt = TT-1;
      const f16* p = h0b + (size_t)(dir ? (TT-1-lt) : lt)*64; sA = (float)p[lane]; }
    L1_CORE(sx1, sn1)
    ring[((it+4)&3)*64 + lane] = sB;                 // row it+4
    { int lt = it+6; if (lt > TT-1) lt = TT-1;
      const f16* p = h0b + (size_t)(dir ? (TT-1-lt) : lt)*64; sB = (float)p[lane]; }
  }
#undef L1_DOTS
#undef L1_CORE

  if (lane < 32) pooled[(size_t)b*64 + dir*32 + j] = (float)psum;
}

// ---------------- FC head: mean -> fc1(relu) -> fc2 ----------------
__global__ void fc_ep(const float* __restrict__ pooled,
                      const float* __restrict__ fc1w, const float* __restrict__ fc1b,
                      const float* __restrict__ fc2w, const float* __restrict__ fc2b,
                      float* __restrict__ out)
{
  int b = blockIdx.x*blockDim.x + threadIdx.x;
  if (b >= TB) return;
  float v[64];
  const float4* p4 = (const float4*)(pooled + (size_t)b*64);
#pragma unroll
  for (int q=0;q<16;q++){ float4 t=p4[q];
    v[4*q]  =t.x*(1.f/TT); v[4*q+1]=t.y*(1.f/TT);
    v[4*q+2]=t.z*(1.f/TT); v[4*q+3]=t.w*(1.f/TT); }
  float acc = fc2b[0];
#pragma unroll
  for (int g=0; g<16; g++){
    float s = fc1b[g];
    const float4* w4 = (const float4*)(fc1w + g*64);
#pragma unroll
    for (int q=0;q<16;q++){ float4 w=w4[q];
      s=fmaf(w.x,v[4*q],s);   s=fmaf(w.y,v[4*q+1],s);
      s=fmaf(w.z,v[4*q+2],s); s=fmaf(w.w,v[4*q+3],s); }
    s = fmaxf(s, 0.f);
    acc = fmaf(fc2w[g], s, acc);
  }
  out[b] = acc;
}

extern "C" void kernel_launch(void* const* d_in, const int* in_sizes, int n_in,
                              void* d_out, int out_size, void* d_ws, size_t ws_size,
                              hipStream_t stream)
{
  (void)in_sizes; (void)n_in; (void)out_size;

  const float* x     = (const float*)d_in[0];
  const float* Wih0f = (const float*)d_in[1];
  const float* Whh0f = (const float*)d_in[2];
  const float* bih0f = (const float*)d_in[3];
  const float* bhh0f = (const float*)d_in[4];
  const float* Wih0b = (const float*)d_in[5];
  const float* Whh0b = (const float*)d_in[6];
  const float* bih0b = (const float*)d_in[7];
  const float* bhh0b = (const float*)d_in[8];
  const float* Wih1f = (const float*)d_in[9];
  const float* Whh1f = (const float*)d_in[10];
  const float* bih1f = (const float*)d_in[11];
  const float* bhh1f = (const float*)d_in[12];
  const float* Wih1b = (const float*)d_in[13];
  const float* Whh1b = (const float*)d_in[14];
  const float* bih1b = (const float*)d_in[15];
  const float* bhh1b = (const float*)d_in[16];
  const float* fc1w  = (const float*)d_in[17];
  const float* fc1b  = (const float*)d_in[18];
  const float* fc2w  = (const float*)d_in[19];
  const float* fc2b  = (const float*)d_in[20];

  // Workspace: pooled [TB][64] fp32 at front, then the h0 region (fp16,
  // 128 MiB -> single chunk). Chunk loop kept for robustness.
  const size_t POOLED_BYTES = (size_t)TB * 64 * sizeof(float);     // 128 KiB
  const size_t PER_B        = (size_t)TT * 64 * sizeof(f16);       // 256 KiB
  float* pooled = (float*)d_ws;
  f16*   h0     = (f16*)((char*)d_ws + POOLED_BYTES);

  size_t avail = (ws_size > POOLED_BYTES) ? (ws_size - POOLED_BYTES) : 0;
  int Bc = (int)(avail / PER_B);
  if (Bc < 1)  Bc = 1;
  if (Bc > TB) Bc = TB;
  int nch = (TB + Bc - 1) / Bc;
  int Bce = (TB + nch - 1) / nch;

  for (int b0 = 0; b0 < TB; b0 += Bce) {
    int bc = (TB - b0 < Bce) ? (TB - b0) : Bce;
    hipLaunchKernelGGL(gru_l0, dim3(2*bc), dim3(64), 0, stream,
                       x + (size_t)b0*TT*6,
                       Wih0f,Whh0f,bih0f,bhh0f, Wih0b,Whh0b,bih0b,bhh0b, h0);
    hipLaunchKernelGGL(gru_l1, dim3(2*bc), dim3(64), 0, stream,
                       h0,
                       Wih1f,Whh1f,bih1f,bhh1f, Wih1b,Whh1b,bih1b,bhh1b,
                       pooled + (size_t)b0*64);
  }
  hipLaunchKernelGGL(fc_ep, dim3(2), dim3(256), 0, stream,
                     pooled, fc1w, fc1b, fc2w, fc2b, (float*)d_out);
}